// Round 6
// baseline (6958.282 us; speedup 1.0000x reference)
//
#include <hip/hip_runtime.h>
#include <hip/hip_bf16.h>
#include <cstddef>

typedef unsigned short u16;
typedef short bf16x8 __attribute__((ext_vector_type(8)));   // 8 bf16 bit-patterns (4 VGPRs)
typedef float f32x4 __attribute__((ext_vector_type(4)));
typedef unsigned short u16x8 __attribute__((ext_vector_type(8)));
typedef unsigned short u16x4 __attribute__((ext_vector_type(4)));

#define MDIM 16384
#define NDIM 512
#define HPAD 520   // 512 + 8 elems: row stride 1040 B (16B-aligned), breaks b128 bank conflicts

__device__ __forceinline__ float b2f(u16 u) {
    return __uint_as_float(((unsigned int)u) << 16);
}
__device__ __forceinline__ u16 f2b(float f) {  // round-to-nearest-even
    unsigned int x = __float_as_uint(f);
    x += 0x7fffu + ((x >> 16) & 1u);
    return (u16)(x >> 16);
}
__device__ __forceinline__ float fast_tanh(float x) {
    // tanh(x) = 1 - 2/(e^{2x}+1); exp overflow -> +1, underflow -> -1 (correct limits)
    float e = __expf(2.0f * x);
    return 1.0f - 2.0f * __builtin_amdgcn_rcpf(e + 1.0f);
}

// ---------------------------------------------------------------------------
// Legacy tiled GEMM (input projection only).
// C(rows x 512) = A(rows x KDIM) * Bt(512 x KDIM)^T + bias(fp32)
// EPI 3: +addf (fp32), write Cf fp32 only        (projection -> state)
template <int KDIM, int EPI, bool AF32>
__global__ __launch_bounds__(256, 2) void gemm_bt(
    const void* __restrict__ Avoid, const u16* __restrict__ Bt,
    const float* __restrict__ bias, const float* __restrict__ addf,
    u16* __restrict__ Cb, float* __restrict__ Cf) {
    __shared__ u16 As[128 * 72];
    __shared__ u16 Bs[128 * 72];
    const int tid = threadIdx.x;
    const int m0 = blockIdx.y * 128;
    const int n0 = blockIdx.x * 128;
    const int lane = tid & 63;
    const int wave = tid >> 6;
    const int wm = (wave & 1) * 64;
    const int wn = (wave >> 1) * 64;
    const int lr = lane & 15;
    const int lk = (lane >> 4) * 8;

    f32x4 acc[4][4];
    f32x4 zero = {0.0f, 0.0f, 0.0f, 0.0f};
#pragma unroll
    for (int i = 0; i < 4; ++i)
#pragma unroll
        for (int j = 0; j < 4; ++j) acc[i][j] = zero;

    const int r0 = tid >> 3;
    const int c0 = (tid & 7) * 8;

    for (int kt = 0; kt < KDIM / 64; ++kt) {
        const int k0 = kt * 64;
#pragma unroll
        for (int it = 0; it < 4; ++it) {
            int r = it * 32 + r0;
            if constexpr (AF32) {
                const float* Af = (const float*)Avoid;
                const float* src = Af + (size_t)(m0 + r) * KDIM + k0 + c0;
                f32x4 lo = *(const f32x4*)(src);
                f32x4 hi = *(const f32x4*)(src + 4);
                u16x8 t;
#pragma unroll
                for (int q = 0; q < 4; ++q) { t[q] = f2b(lo[q]); t[q + 4] = f2b(hi[q]); }
                *(u16x8*)(&As[r * 72 + c0]) = t;
            } else {
                const u16* Ab = (const u16*)Avoid;
                *(f32x4*)(&As[r * 72 + c0]) =
                    *(const f32x4*)(Ab + (size_t)(m0 + r) * KDIM + k0 + c0);
            }
            *(f32x4*)(&Bs[r * 72 + c0]) =
                *(const f32x4*)(Bt + (size_t)(n0 + r) * KDIM + k0 + c0);
        }
        __syncthreads();
#pragma unroll
        for (int kk = 0; kk < 2; ++kk) {
            bf16x8 af[4], bw[4];
#pragma unroll
            for (int i = 0; i < 4; ++i) {
                af[i] = __builtin_bit_cast(
                    bf16x8, *(const f32x4*)(&As[(wm + i * 16 + lr) * 72 + kk * 32 + lk]));
                bw[i] = __builtin_bit_cast(
                    bf16x8, *(const f32x4*)(&Bs[(wn + i * 16 + lr) * 72 + kk * 32 + lk]));
            }
#pragma unroll
            for (int i = 0; i < 4; ++i)
#pragma unroll
                for (int j = 0; j < 4; ++j)
                    acc[i][j] = __builtin_amdgcn_mfma_f32_16x16x32_bf16(
                        af[i], bw[j], acc[i][j], 0, 0, 0);
        }
        __syncthreads();
    }
#pragma unroll
    for (int j = 0; j < 4; ++j) {
        const int col = n0 + wn + j * 16 + lr;
        const float bv = bias[col];
#pragma unroll
        for (int i = 0; i < 4; ++i) {
            const int rowb = m0 + wm + i * 16 + (lane >> 4) * 4;
#pragma unroll
            for (int r = 0; r < 4; ++r) {
                float v = acc[i][j][r] + bv;
                size_t off = (size_t)(rowb + r) * NDIM + col;
                if constexpr (EPI == 2) Cb[off] = f2b(v);
                if constexpr (EPI == 3) {
                    v += addf[off];
                    Cf[off] = v;
                }
            }
        }
    }
}

// ---------------------------------------------------------------------------
// Mega-fused dopri5, no-spill + coalesced-K + weight-prefetch edition.
// Block = 64 rows, 512 threads (8 waves, each owns a 64-col strip of N=512).
// Fragment layout: element (i,j,r) <-> row = i*16+(lane>>4)*4+r, col = wn+j*16+(lane&15)
// - S: f32x4 S[4][4] registers for the whole solve (64 VGPRs).
// - Newest k: u16x4 kA[4][4] (32 VGPRs). k1..k5 in global bf16 scratch G1..G5,
//   layout [block][fragpair fg][tid] as u16x8: off = block*32768 + fg*4096 + tid*8
//   -> lane stride 8 u16 = 16 B -> 1 KB/wave contiguous per access (coalesced
//   BOTH for loads and stores; R5 had [tid][frag] which was 8x amplified).
// - amdgpu_waves_per_eu(2,2): 130 KB LDS forces 1 block/CU = 2 waves/SIMD, so
//   the allocator may use the full 256-VGPR budget -> no scratch spills
//   (R3-R5 allocated 112-128 VGPRs for a ~200-reg live set and spilled).
// - LAYER: fully-unrolled kt loop with double-buffered weight fragments,
//   issuing kt+1/kt+2 B-loads before kt's MFMAs (hides L2 latency).
__global__ __launch_bounds__(512)
__attribute__((amdgpu_waves_per_eu(2, 2)))
void ode_mega(
    const float* __restrict__ S32,
    const u16* __restrict__ W1t, const float* __restrict__ bb1,
    const u16* __restrict__ W2t, const float* __restrict__ bb2,
    const u16* __restrict__ W3t, const float* __restrict__ bb3,
    u16* __restrict__ G1, u16* __restrict__ G2, u16* __restrict__ G3,
    u16* __restrict__ G4, u16* __restrict__ G5,
    float* __restrict__ OUT) {
    __shared__ u16 As[64 * HPAD];
    __shared__ u16 Hs[64 * HPAD];
    const int tid = threadIdx.x;
    const int lane = tid & 63;
    const int wn = (tid >> 6) * 64;   // wave's 64-col strip
    const int lr = lane & 15;
    const int lq = lane >> 4;         // 0..3
    const int lk = lq * 8;
    const size_t row0 = (size_t)blockIdx.x * 64;
    const size_t kbF = (size_t)blockIdx.x * 32768 + (size_t)tid * 8;

    constexpr double h = 0.1 / 8.0;
    constexpr float A21 = (float)(h * 1.0 / 5.0);
    constexpr float A31 = (float)(h * 3.0 / 40.0), A32 = (float)(h * 9.0 / 40.0);
    constexpr float A41 = (float)(h * 44.0 / 45.0), A42 = (float)(h * -56.0 / 15.0);
    constexpr float A43 = (float)(h * 32.0 / 9.0);
    constexpr float A51 = (float)(h * 19372.0 / 6561.0), A52 = (float)(h * -25360.0 / 2187.0);
    constexpr float A53 = (float)(h * 64448.0 / 6561.0), A54 = (float)(h * -212.0 / 729.0);
    constexpr float A61 = (float)(h * 9017.0 / 3168.0), A62 = (float)(h * -355.0 / 33.0);
    constexpr float A63 = (float)(h * 46732.0 / 5247.0), A64 = (float)(h * 49.0 / 176.0);
    constexpr float A65 = (float)(h * -5103.0 / 18656.0);
    constexpr float B1c = (float)(h * 35.0 / 384.0), B3c = (float)(h * 500.0 / 1113.0);
    constexpr float B4c = (float)(h * 125.0 / 192.0), B5c = (float)(h * -2187.0 / 6784.0);
    constexpr float B6c = (float)(h * 11.0 / 84.0);

    const f32x4 zf = {0.f, 0.f, 0.f, 0.f};
    f32x4 S[4][4];
#pragma unroll
    for (int i = 0; i < 4; ++i)
#pragma unroll
        for (int j = 0; j < 4; ++j) {
#pragma unroll
            for (int r = 0; r < 4; ++r)
                S[i][j][r] = S32[(row0 + i * 16 + lq * 4 + r) * 512 + wn + j * 16 + lr];
        }

    u16x4 kA[4][4];
    f32x4 acc[4][4];

// stage: As = f2b(S + C0*P0 + C1*P1 + C2*P2 + C3*P3 + CKA*kA); PERSIST -> S=sv
#define STAGE(NG, UKA, PERSIST, P0, P1, P2, P3, C0, C1, C2, C3, CKA)               \
    do {                                                                           \
        _Pragma("unroll 2") for (int fg = 0; fg < 8; ++fg) {                       \
            u16x8 gv0, gv1, gv2, gv3;                                              \
            if (NG >= 1) gv0 = *(const u16x8*)((P0) + kbF + fg * 4096);            \
            if (NG >= 2) gv1 = *(const u16x8*)((P1) + kbF + fg * 4096);            \
            if (NG >= 3) gv2 = *(const u16x8*)((P2) + kbF + fg * 4096);            \
            if (NG >= 4) gv3 = *(const u16x8*)((P3) + kbF + fg * 4096);            \
            _Pragma("unroll") for (int hf = 0; hf < 2; ++hf) {                     \
                const int f_ = fg * 2 + hf;                                        \
                const int i_ = f_ >> 2, j_ = f_ & 3;                               \
                f32x4 sv = S[i_][j_];                                              \
                _Pragma("unroll") for (int r_ = 0; r_ < 4; ++r_) {                 \
                    float a_ = sv[r_];                                             \
                    if (NG >= 1) a_ += (C0) * b2f(gv0[hf * 4 + r_]);               \
                    if (NG >= 2) a_ += (C1) * b2f(gv1[hf * 4 + r_]);               \
                    if (NG >= 3) a_ += (C2) * b2f(gv2[hf * 4 + r_]);               \
                    if (NG >= 4) a_ += (C3) * b2f(gv3[hf * 4 + r_]);               \
                    if (UKA) a_ += (CKA) * b2f(kA[i_][j_][r_]);                    \
                    sv[r_] = a_;                                                   \
                }                                                                  \
                if (PERSIST) S[i_][j_] = sv;                                       \
                const int col_ = wn + j_ * 16 + lr;                                \
                const int rw_ = i_ * 16 + lq * 4;                                  \
                As[(rw_ + 0) * HPAD + col_] = f2b(sv[0]);                          \
                As[(rw_ + 1) * HPAD + col_] = f2b(sv[1]);                          \
                As[(rw_ + 2) * HPAD + col_] = f2b(sv[2]);                          \
                As[(rw_ + 3) * HPAD + col_] = f2b(sv[3]);                          \
            }                                                                      \
        }                                                                          \
    } while (0)

#define LD_BW(DST, WT, KT)                                                         \
    {                                                                              \
        _Pragma("unroll") for (int j_ = 0; j_ < 4; ++j_)                           \
            DST[j_] = __builtin_bit_cast(bf16x8,                                   \
                *(const f32x4*)((WT) + (size_t)((wn + j_ * 16 + lr) << 9) +        \
                                (KT) * 32 + lk));                                  \
    }

#define LD_AF(DST, SRC, KT)                                                        \
    {                                                                              \
        _Pragma("unroll") for (int i_ = 0; i_ < 4; ++i_)                           \
            DST[i_] = __builtin_bit_cast(bf16x8,                                   \
                *(const f32x4*)(&(SRC)[(i_ * 16 + lr) * HPAD + (KT) * 32 + lk])); \
    }

#define MFMA16(AF, BW)                                                             \
    {                                                                              \
        _Pragma("unroll") for (int i_ = 0; i_ < 4; ++i_)                           \
            _Pragma("unroll") for (int j_ = 0; j_ < 4; ++j_)                       \
                acc[i_][j_] = __builtin_amdgcn_mfma_f32_16x16x32_bf16(             \
                    (AF)[i_], (BW)[j_], acc[i_][j_], 0, 0, 0);                     \
    }

// layer with software-pipelined weight fetch (bw for kt+1/kt+2 issued before
// kt's MFMAs). Fully unrolled; compiler renames afC per iteration.
#define LAYER(SRC, WT)                                                             \
    do {                                                                           \
        _Pragma("unroll") for (int i_ = 0; i_ < 4; ++i_)                           \
            _Pragma("unroll") for (int j_ = 0; j_ < 4; ++j_) acc[i_][j_] = zf;     \
        bf16x8 bwA[4], bwB[4], afC[4];                                             \
        LD_BW(bwA, WT, 0)                                                          \
        _Pragma("unroll") for (int kt = 0; kt < 16; kt += 2) {                     \
            LD_BW(bwB, WT, kt + 1)                                                 \
            LD_AF(afC, SRC, kt)                                                    \
            MFMA16(afC, bwA)                                                       \
            if (kt + 2 < 16) LD_BW(bwA, WT, kt + 2)                                \
            LD_AF(afC, SRC, kt + 1)                                                \
            MFMA16(afC, bwB)                                                       \
        }                                                                          \
    } while (0)

#define EPI_TANH(BIAS, DST)                                                        \
    do {                                                                           \
        _Pragma("unroll") for (int j_ = 0; j_ < 4; ++j_) {                         \
            const float bv = BIAS[wn + j_ * 16 + lr];                              \
            _Pragma("unroll") for (int i_ = 0; i_ < 4; ++i_) {                     \
                const int rb = i_ * 16 + lq * 4;                                   \
                _Pragma("unroll") for (int r_ = 0; r_ < 4; ++r_)                   \
                    DST[(rb + r_) * HPAD + wn + j_ * 16 + lr] =                    \
                        f2b(fast_tanh(acc[i_][j_][r_] + bv));                      \
            }                                                                      \
        }                                                                          \
    } while (0)

// layer-3 epilogue: kA = f2b(acc + b3); optional coalesced store to G
#define EPI_K(GP)                                                                  \
    do {                                                                           \
        _Pragma("unroll") for (int j_ = 0; j_ < 4; ++j_) {                         \
            const float bv = bb3[wn + j_ * 16 + lr];                               \
            _Pragma("unroll") for (int i_ = 0; i_ < 4; ++i_) {                     \
                u16x4 kv;                                                          \
                _Pragma("unroll") for (int r_ = 0; r_ < 4; ++r_)                   \
                    kv[r_] = f2b(acc[i_][j_][r_] + bv);                            \
                kA[i_][j_] = kv;                                                   \
            }                                                                      \
        }                                                                          \
        if ((GP) != nullptr) {                                                     \
            _Pragma("unroll") for (int fg = 0; fg < 8; ++fg) {                     \
                const int f0 = fg * 2;                                             \
                const int i_ = f0 >> 2, j0 = f0 & 3;                               \
                u16x8 w;                                                           \
                _Pragma("unroll") for (int r_ = 0; r_ < 4; ++r_) {                 \
                    w[r_] = kA[i_][j0][r_];                                        \
                    w[r_ + 4] = kA[i_][j0 + 1][r_];                                \
                }                                                                  \
                *(u16x8*)((u16*)(GP) + kbF + fg * 4096) = w;                       \
            }                                                                      \
        }                                                                          \
    } while (0)

// full MLP after stage (As staged); 4 barriers per eval
#define MLP3(GP)                                                                   \
    do {                                                                           \
        __syncthreads();                                                           \
        LAYER(As, W1t);                                                            \
        EPI_TANH(bb1, Hs);                                                         \
        __syncthreads();                                                           \
        LAYER(Hs, W2t);                                                            \
        EPI_TANH(bb2, As);                                                         \
        __syncthreads();                                                           \
        LAYER(As, W3t);                                                            \
        __syncthreads();                                                           \
        EPI_K(GP);                                                                 \
    } while (0)

#pragma clang loop unroll(disable)
    for (int st = 0; st < 8; ++st) {
        // e0: (st>0: fused state update S += sum B*k) ; stage s1 = S
        if (st == 0)
            STAGE(0, 0, 0, G1, G1, G1, G1, 0.f, 0.f, 0.f, 0.f, 0.f);
        else
            STAGE(4, 1, 1, G1, G3, G4, G5, B1c, B3c, B4c, B5c, B6c);
        MLP3(G1);                                     // k1 -> kA, G1

        // e1: s2 = S + A21*k1(kA)
        STAGE(0, 1, 0, G1, G1, G1, G1, 0.f, 0.f, 0.f, 0.f, A21);
        MLP3(G2);                                     // k2 -> kA, G2

        // e2: s3 = S + A31*k1(G1) + A32*k2(kA)
        STAGE(1, 1, 0, G1, G1, G1, G1, A31, 0.f, 0.f, 0.f, A32);
        MLP3(G3);                                     // k3 -> kA, G3

        // e3: s4 = S + A41*k1 + A42*k2 + A43*k3(kA)
        STAGE(2, 1, 0, G1, G2, G2, G2, A41, A42, 0.f, 0.f, A43);
        MLP3(G4);                                     // k4 -> kA, G4

        // e4: s5 = S + A51*k1 + A52*k2 + A53*k3 + A54*k4(kA)
        STAGE(3, 1, 0, G1, G2, G3, G3, A51, A52, A53, 0.f, A54);
        MLP3(G5);                                     // k5 -> kA, G5

        // e5: s6 = S + A61*k1 + A62*k2 + A63*k3 + A64*k4 + A65*k5(kA)
        STAGE(4, 1, 0, G1, G2, G3, G4, A61, A62, A63, A64, A65);
        MLP3((u16*)nullptr);                          // k6 -> kA only
    }

    // final state update + row-major OUT write
#pragma unroll 2
    for (int fg = 0; fg < 8; ++fg) {
        u16x8 g1v = *(const u16x8*)(G1 + kbF + fg * 4096);
        u16x8 g3v = *(const u16x8*)(G3 + kbF + fg * 4096);
        u16x8 g4v = *(const u16x8*)(G4 + kbF + fg * 4096);
        u16x8 g5v = *(const u16x8*)(G5 + kbF + fg * 4096);
#pragma unroll
        for (int hf = 0; hf < 2; ++hf) {
            const int f = fg * 2 + hf;
            const int i = f >> 2, j = f & 3;
            const int col = wn + j * 16 + lr;
            const int rw = i * 16 + lq * 4;
#pragma unroll
            for (int r = 0; r < 4; ++r) {
                float v = S[i][j][r] + B1c * b2f(g1v[hf * 4 + r]) +
                          B3c * b2f(g3v[hf * 4 + r]) + B4c * b2f(g4v[hf * 4 + r]) +
                          B5c * b2f(g5v[hf * 4 + r]) + B6c * b2f(kA[i][j][r]);
                OUT[(row0 + rw + r) * 512 + col] = v;
            }
        }
    }
#undef MLP3
#undef EPI_K
#undef EPI_TANH
#undef LAYER
#undef MFMA16
#undef LD_AF
#undef LD_BW
#undef STAGE
}

// out_bf16[c*R + r] = in_f32[r*Ncols + c]   (weight transpose + cast, tiny)
__global__ void transpose_k(const float* __restrict__ in, u16* __restrict__ out,
                            int R, int Ncols) {
    int idx = blockIdx.x * 256 + threadIdx.x;
    int r = idx / Ncols, c = idx % Ncols;
    out[(size_t)c * R + r] = f2b(in[idx]);
}

extern "C" void kernel_launch(void* const* d_in, const int* in_sizes, int n_in,
                              void* d_out, int out_size, void* d_ws, size_t ws_size,
                              hipStream_t stream) {
    // ---- order-robust input mapping via in_sizes ----
    const float *y = nullptr, *u_t = nullptr, *Wp = nullptr, *bp = nullptr;
    const float *W1 = nullptr, *b1 = nullptr, *W2 = nullptr, *b2 = nullptr;
    const float *W3 = nullptr, *b3 = nullptr;
    {
        const float* w262[3] = {nullptr, nullptr, nullptr};
        const float* s512[4] = {nullptr, nullptr, nullptr, nullptr};
        int i512[4] = {0, 0, 0, 0};
        int n262 = 0, n512 = 0;
        for (int i = 0; i < n_in; ++i) {
            const float* p = (const float*)d_in[i];
            int sz = in_sizes[i];
            if (sz == MDIM * NDIM) y = p;
            else if (sz == MDIM * 256) u_t = p;
            else if (sz == 256 * 512) Wp = p;
            else if (sz == 512 * 512) { if (n262 < 3) w262[n262++] = p; }
            else if (sz == 512) { if (n512 < 4) { i512[n512] = i; s512[n512++] = p; } }
        }
        W1 = w262[0]; W2 = w262[1]; W3 = w262[2];
        bool contig = (n512 == 4) && (i512[3] == i512[0] + 3);
        if (contig) { b1 = s512[0]; b2 = s512[1]; b3 = s512[2]; bp = s512[3]; }
        else        { bp = s512[0]; b1 = s512[1]; b2 = s512[2]; b3 = s512[3]; }
        if (!y || !u_t || !Wp || !W1 || n512 < 4) {  // fallback: dict order
            y  = (const float*)d_in[0]; u_t = (const float*)d_in[1];
            Wp = (const float*)d_in[2]; bp  = (const float*)d_in[3];
            W1 = (const float*)d_in[4]; b1  = (const float*)d_in[5];
            W2 = (const float*)d_in[6]; b2  = (const float*)d_in[7];
            W3 = (const float*)d_in[8]; b3  = (const float*)d_in[9];
        }
    }

    u16* ws  = (u16*)d_ws;
    u16* Wpt = ws;                    // 512x256 bf16  (N x K, K contiguous)
    u16* W1t = Wpt + 512 * 256;       // 512x512 bf16
    u16* W2t = W1t + 512 * 512;
    u16* W3t = W2t + 512 * 512;
    const size_t wfix = 512 * 256 + 3 * 512 * 512;   // 917504 u16 = 1.84 MB

    // per-row workspace: S32 fp32 (1024 u16) + K1..K5 fragment-packed bf16 (5*512 u16)
    long wsElems = (long)(ws_size / 2);
    long chunk = (wsElems - (long)wfix) / (7L * NDIM);
    chunk = (chunk / 128) * 128;
    if (chunk > MDIM) chunk = MDIM;
    if (chunk < 128) chunk = 128;

    transpose_k<<<512, 256, 0, stream>>>(Wp, Wpt, 256, 512);
    transpose_k<<<1024, 256, 0, stream>>>(W1, W1t, 512, 512);
    transpose_k<<<1024, 256, 0, stream>>>(W2, W2t, 512, 512);
    transpose_k<<<1024, 256, 0, stream>>>(W3, W3t, 512, 512);

    float* OUT = (float*)d_out;   // fp32 output, per reference dtype

    for (long row0 = 0; row0 < MDIM; row0 += chunk) {
        const long rows = (MDIM - row0 < chunk) ? (MDIM - row0) : chunk;
        const size_t CB = (size_t)rows * NDIM;

        u16* base = ws + wfix;
        float* S32 = (float*)base;          // 2*CB u16
        u16* G1 = base + 2 * CB;
        u16* G2 = base + 3 * CB;
        u16* G3 = base + 4 * CB;
        u16* G4 = base + 5 * CB;
        u16* G5 = base + 6 * CB;

        // S32 = u_t @ Wp + bp + y  (fp32 only)
        dim3 gg(4, (unsigned)(rows / 128));
        gemm_bt<256, 3, true><<<gg, 256, 0, stream>>>(
            (const void*)(u_t + (size_t)row0 * 256), Wpt, bp,
            y + (size_t)row0 * NDIM, nullptr, S32);

        // all 8 steps x 6 evals fused; S + newest k in registers, no spills
        const int nb = (int)(rows / 64);
        ode_mega<<<nb, 512, 0, stream>>>(
            S32, W1t, b1, W2t, b2, W3t, b3,
            G1, G2, G3, G4, G5,
            OUT + (size_t)row0 * NDIM);
    }
}

// Round 7
// 5006.022 us; speedup vs baseline: 1.3900x; 1.3900x over previous
//
#include <hip/hip_runtime.h>
#include <hip/hip_bf16.h>
#include <cstddef>

typedef unsigned short u16;
typedef short bf16x8 __attribute__((ext_vector_type(8)));   // 8 bf16 bit-patterns (4 VGPRs)
typedef float f32x4 __attribute__((ext_vector_type(4)));
typedef unsigned short u16x8 __attribute__((ext_vector_type(8)));
typedef unsigned short u16x4 __attribute__((ext_vector_type(4)));

#define MDIM 16384
#define NDIM 512
#define HPAD 520   // 512 + 8 elems: row stride 1040 B (16B-aligned), breaks b128 bank conflicts

__device__ __forceinline__ float b2f(u16 u) {
    return __uint_as_float(((unsigned int)u) << 16);
}
__device__ __forceinline__ u16 f2b(float f) {  // round-to-nearest-even
    unsigned int x = __float_as_uint(f);
    x += 0x7fffu + ((x >> 16) & 1u);
    return (u16)(x >> 16);
}
__device__ __forceinline__ float fast_tanh(float x) {
    // tanh(x) = 1 - 2/(e^{2x}+1); exp overflow -> +1, underflow -> -1 (correct limits)
    float e = __expf(2.0f * x);
    return 1.0f - 2.0f * __builtin_amdgcn_rcpf(e + 1.0f);
}

// ---------------------------------------------------------------------------
// Legacy tiled GEMM (input projection only).
// C(rows x 512) = A(rows x KDIM) * Bt(512 x KDIM)^T + bias(fp32)
// EPI 3: +addf (fp32), write Cf fp32 only        (projection -> state)
template <int KDIM, int EPI, bool AF32>
__global__ __launch_bounds__(256, 2) void gemm_bt(
    const void* __restrict__ Avoid, const u16* __restrict__ Bt,
    const float* __restrict__ bias, const float* __restrict__ addf,
    u16* __restrict__ Cb, float* __restrict__ Cf) {
    __shared__ u16 As[128 * 72];
    __shared__ u16 Bs[128 * 72];
    const int tid = threadIdx.x;
    const int m0 = blockIdx.y * 128;
    const int n0 = blockIdx.x * 128;
    const int lane = tid & 63;
    const int wave = tid >> 6;
    const int wm = (wave & 1) * 64;
    const int wn = (wave >> 1) * 64;
    const int lr = lane & 15;
    const int lk = (lane >> 4) * 8;

    f32x4 acc[4][4];
    f32x4 zero = {0.0f, 0.0f, 0.0f, 0.0f};
#pragma unroll
    for (int i = 0; i < 4; ++i)
#pragma unroll
        for (int j = 0; j < 4; ++j) acc[i][j] = zero;

    const int r0 = tid >> 3;
    const int c0 = (tid & 7) * 8;

    for (int kt = 0; kt < KDIM / 64; ++kt) {
        const int k0 = kt * 64;
#pragma unroll
        for (int it = 0; it < 4; ++it) {
            int r = it * 32 + r0;
            if constexpr (AF32) {
                const float* Af = (const float*)Avoid;
                const float* src = Af + (size_t)(m0 + r) * KDIM + k0 + c0;
                f32x4 lo = *(const f32x4*)(src);
                f32x4 hi = *(const f32x4*)(src + 4);
                u16x8 t;
#pragma unroll
                for (int q = 0; q < 4; ++q) { t[q] = f2b(lo[q]); t[q + 4] = f2b(hi[q]); }
                *(u16x8*)(&As[r * 72 + c0]) = t;
            } else {
                const u16* Ab = (const u16*)Avoid;
                *(f32x4*)(&As[r * 72 + c0]) =
                    *(const f32x4*)(Ab + (size_t)(m0 + r) * KDIM + k0 + c0);
            }
            *(f32x4*)(&Bs[r * 72 + c0]) =
                *(const f32x4*)(Bt + (size_t)(n0 + r) * KDIM + k0 + c0);
        }
        __syncthreads();
#pragma unroll
        for (int kk = 0; kk < 2; ++kk) {
            bf16x8 af[4], bw[4];
#pragma unroll
            for (int i = 0; i < 4; ++i) {
                af[i] = __builtin_bit_cast(
                    bf16x8, *(const f32x4*)(&As[(wm + i * 16 + lr) * 72 + kk * 32 + lk]));
                bw[i] = __builtin_bit_cast(
                    bf16x8, *(const f32x4*)(&Bs[(wn + i * 16 + lr) * 72 + kk * 32 + lk]));
            }
#pragma unroll
            for (int i = 0; i < 4; ++i)
#pragma unroll
                for (int j = 0; j < 4; ++j)
                    acc[i][j] = __builtin_amdgcn_mfma_f32_16x16x32_bf16(
                        af[i], bw[j], acc[i][j], 0, 0, 0);
        }
        __syncthreads();
    }
#pragma unroll
    for (int j = 0; j < 4; ++j) {
        const int col = n0 + wn + j * 16 + lr;
        const float bv = bias[col];
#pragma unroll
        for (int i = 0; i < 4; ++i) {
            const int rowb = m0 + wm + i * 16 + (lane >> 4) * 4;
#pragma unroll
            for (int r = 0; r < 4; ++r) {
                float v = acc[i][j][r] + bv;
                size_t off = (size_t)(rowb + r) * NDIM + col;
                if constexpr (EPI == 2) Cb[off] = f2b(v);
                if constexpr (EPI == 3) {
                    v += addf[off];
                    Cf[off] = v;
                }
            }
        }
    }
}

// ---------------------------------------------------------------------------
// Fused dopri5 stage (32-row tile, 2 blocks/CU edition).
// K_out = f(S32 + sum c_i K_i), f = 3-layer MLP.
// Block = 32 batch rows, 512 threads (8 waves, each owns a 64-col strip).
// LDS = 2 x 32x520 bf16 = 66.6 KB -> TWO blocks co-resident per CU; the two
// blocks run phase-shifted, so one block's MFMA/weight-stream covers the
// other's staging latency, tanh VALU and barrier drains (m114 overlap).
// 16 waves/CU = 4 waves/SIMD; VGPR ~70 << 128 cap -> no spills.
// Weights streamed from L2 as direct MFMA B-fragments (full W per block).
// WS: write the fp32 combo back to S32out (fuses the previous step's final
// state update into this stage's staging pass). All buffer accesses are
// block-row-local, so in-place S32 / K1 update is race-free.
template <int NT, bool WS>
__global__ __launch_bounds__(512, 4) void ode_eval(
    const float* __restrict__ S32, float* __restrict__ S32out,
    const u16* __restrict__ P1, const u16* __restrict__ P2,
    const u16* __restrict__ P3, const u16* __restrict__ P4,
    const u16* __restrict__ P5,
    float c1, float c2, float c3, float c4, float c5,
    const u16* __restrict__ W1t, const float* __restrict__ bb1,
    const u16* __restrict__ W2t, const float* __restrict__ bb2,
    const u16* __restrict__ W3t, const float* __restrict__ bb3,
    u16* __restrict__ Kout) {
    __shared__ u16 As[32 * HPAD];
    __shared__ u16 Hs[32 * HPAD];
    const int tid = threadIdx.x;
    const int lane = tid & 63;
    const int wn = (tid >> 6) * 64;      // wave's 64-col strip in N=512
    const int lr = lane & 15;
    const int lq = lane >> 4;
    const int lk = lq * 8;
    const size_t row0 = (size_t)blockIdx.x * 32;

    // ---- stage s = S32 + sum c_i K_i -> bf16 As; optionally write fp32 back
    {
        const u16* kp[5] = {P1, P2, P3, P4, P5};
        const float cs[5] = {c1, c2, c3, c4, c5};
#pragma unroll
        for (int it = tid; it < 2048; it += 512) {   // 32 rows x 64 chunks of 8
            const int r = it >> 6;
            const int c8 = (it & 63) << 3;
            const size_t g = (row0 + r) * 512 + c8;
            f32x4 lo = *(const f32x4*)(S32 + g);
            f32x4 hi = *(const f32x4*)(S32 + g + 4);
#pragma unroll
            for (int t = 0; t < NT; ++t) {
                u16x8 v = *(const u16x8*)(kp[t] + g);
#pragma unroll
                for (int q = 0; q < 4; ++q) {
                    lo[q] += cs[t] * b2f(v[q]);
                    hi[q] += cs[t] * b2f(v[q + 4]);
                }
            }
            if constexpr (WS) {
                *(f32x4*)(S32out + g) = lo;
                *(f32x4*)(S32out + g + 4) = hi;
            }
            u16x8 o;
#pragma unroll
            for (int q = 0; q < 4; ++q) { o[q] = f2b(lo[q]); o[q + 4] = f2b(hi[q]); }
            *(u16x8*)(&As[r * HPAD + c8]) = o;
        }
    }
    __syncthreads();

    // One MLP layer: SRC(LDS 32xHPAD bf16) @ WT(global [512][512] N-major)^T
    // + BIAS -> DST(LDS), optional tanh. Per wave: 2 row-tiles x 4 col-tiles.
#define MLP_LAYER(SRC, WT, BIAS, DST, DO_TANH)                                     \
    {                                                                              \
        f32x4 acc[2][4];                                                           \
        _Pragma("unroll") for (int i = 0; i < 2; ++i)                              \
            _Pragma("unroll") for (int j = 0; j < 4; ++j)                          \
                acc[i][j] = (f32x4){0.0f, 0.0f, 0.0f, 0.0f};                       \
        _Pragma("unroll 4") for (int kt = 0; kt < 16; ++kt) {                      \
            bf16x8 af[2], bw[4];                                                   \
            _Pragma("unroll") for (int j = 0; j < 4; ++j)                          \
                bw[j] = __builtin_bit_cast(bf16x8,                                 \
                    *(const f32x4*)(WT + (size_t)((wn + j * 16 + lr) << 9) +       \
                                    kt * 32 + lk));                                \
            _Pragma("unroll") for (int i = 0; i < 2; ++i)                          \
                af[i] = __builtin_bit_cast(bf16x8,                                 \
                    *(const f32x4*)(&SRC[(i * 16 + lr) * HPAD + kt * 32 + lk]));   \
            _Pragma("unroll") for (int i = 0; i < 2; ++i)                          \
                _Pragma("unroll") for (int j = 0; j < 4; ++j)                      \
                    acc[i][j] = __builtin_amdgcn_mfma_f32_16x16x32_bf16(           \
                        af[i], bw[j], acc[i][j], 0, 0, 0);                         \
        }                                                                          \
        _Pragma("unroll") for (int j = 0; j < 4; ++j) {                            \
            const float bv = BIAS[wn + j * 16 + lr];                               \
            _Pragma("unroll") for (int i = 0; i < 2; ++i) {                        \
                const int rb = i * 16 + lq * 4;                                    \
                _Pragma("unroll") for (int r = 0; r < 4; ++r) {                    \
                    float v = acc[i][j][r] + bv;                                   \
                    if (DO_TANH) v = fast_tanh(v);                                 \
                    DST[(rb + r) * HPAD + wn + j * 16 + lr] = f2b(v);              \
                }                                                                  \
            }                                                                      \
        }                                                                          \
    }

    MLP_LAYER(As, W1t, bb1, Hs, true);
    __syncthreads();
    MLP_LAYER(Hs, W2t, bb2, As, true);
    __syncthreads();
    MLP_LAYER(As, W3t, bb3, Hs, false);
    __syncthreads();
#undef MLP_LAYER

    // coalesced bf16 K write from LDS
#pragma unroll
    for (int it = tid; it < 2048; it += 512) {
        const int r = it >> 6;
        const int c8 = (it & 63) << 3;
        *(f32x4*)(Kout + (row0 + r) * 512 + c8) = *(const f32x4*)(&Hs[r * HPAD + c8]);
    }
}

// out_bf16[c*R + r] = in_f32[r*Ncols + c]   (weight transpose + cast, tiny)
__global__ void transpose_k(const float* __restrict__ in, u16* __restrict__ out,
                            int R, int Ncols) {
    int idx = blockIdx.x * 256 + threadIdx.x;
    int r = idx / Ncols, c = idx % Ncols;
    out[(size_t)c * R + r] = f2b(in[idx]);
}

// a = S32 + c1*p1 + ... (p's bf16); write outB bf16 (opt), outF fp32 (opt)
__global__ __launch_bounds__(256) void combo(
    const float* __restrict__ S32,
    const u16* __restrict__ p1, const u16* __restrict__ p2,
    const u16* __restrict__ p3, const u16* __restrict__ p4,
    const u16* __restrict__ p5,
    float c1, float c2, float c3, float c4, float c5, int nterms,
    float* __restrict__ outF, u16* __restrict__ outB) {
    size_t off = ((size_t)blockIdx.x * 256 + threadIdx.x) * 4;
    f32x4 a = *(const f32x4*)(S32 + off);
    const u16* ps[5] = {p1, p2, p3, p4, p5};
    float cs[5] = {c1, c2, c3, c4, c5};
    for (int t = 0; t < nterms; ++t) {
        u16x4 v = *(const u16x4*)(ps[t] + off);
#pragma unroll
        for (int i = 0; i < 4; ++i) a[i] += cs[t] * b2f(v[i]);
    }
    if (outF) *(f32x4*)(outF + off) = a;
    if (outB) {
        u16x4 o;
#pragma unroll
        for (int i = 0; i < 4; ++i) o[i] = f2b(a[i]);
        *(u16x4*)(outB + off) = o;
    }
}

extern "C" void kernel_launch(void* const* d_in, const int* in_sizes, int n_in,
                              void* d_out, int out_size, void* d_ws, size_t ws_size,
                              hipStream_t stream) {
    // ---- order-robust input mapping via in_sizes ----
    const float *y = nullptr, *u_t = nullptr, *Wp = nullptr, *bp = nullptr;
    const float *W1 = nullptr, *b1 = nullptr, *W2 = nullptr, *b2 = nullptr;
    const float *W3 = nullptr, *b3 = nullptr;
    {
        const float* w262[3] = {nullptr, nullptr, nullptr};
        const float* s512[4] = {nullptr, nullptr, nullptr, nullptr};
        int i512[4] = {0, 0, 0, 0};
        int n262 = 0, n512 = 0;
        for (int i = 0; i < n_in; ++i) {
            const float* p = (const float*)d_in[i];
            int sz = in_sizes[i];
            if (sz == MDIM * NDIM) y = p;
            else if (sz == MDIM * 256) u_t = p;
            else if (sz == 256 * 512) Wp = p;
            else if (sz == 512 * 512) { if (n262 < 3) w262[n262++] = p; }
            else if (sz == 512) { if (n512 < 4) { i512[n512] = i; s512[n512++] = p; } }
        }
        W1 = w262[0]; W2 = w262[1]; W3 = w262[2];
        bool contig = (n512 == 4) && (i512[3] == i512[0] + 3);
        if (contig) { b1 = s512[0]; b2 = s512[1]; b3 = s512[2]; bp = s512[3]; }
        else        { bp = s512[0]; b1 = s512[1]; b2 = s512[2]; b3 = s512[3]; }
        if (!y || !u_t || !Wp || !W1 || n512 < 4) {  // fallback: dict order
            y  = (const float*)d_in[0]; u_t = (const float*)d_in[1];
            Wp = (const float*)d_in[2]; bp  = (const float*)d_in[3];
            W1 = (const float*)d_in[4]; b1  = (const float*)d_in[5];
            W2 = (const float*)d_in[6]; b2  = (const float*)d_in[7];
            W3 = (const float*)d_in[8]; b3  = (const float*)d_in[9];
        }
    }

    u16* ws  = (u16*)d_ws;
    u16* Wpt = ws;                    // 512x256 bf16  (N x K, K contiguous)
    u16* W1t = Wpt + 512 * 256;       // 512x512 bf16
    u16* W2t = W1t + 512 * 512;
    u16* W3t = W2t + 512 * 512;
    const size_t wfix = 512 * 256 + 3 * 512 * 512;   // 917504 u16 = 1.84 MB

    // per-row workspace: S32 fp32 (1024 u16) + K1..K5 bf16 (5*512 u16)
    long wsElems = (long)(ws_size / 2);
    long chunk = (wsElems - (long)wfix) / (7L * NDIM);
    chunk = (chunk / 128) * 128;
    if (chunk > MDIM) chunk = MDIM;
    if (chunk < 128) chunk = 128;

    transpose_k<<<512, 256, 0, stream>>>(Wp, Wpt, 256, 512);
    transpose_k<<<1024, 256, 0, stream>>>(W1, W1t, 512, 512);
    transpose_k<<<1024, 256, 0, stream>>>(W2, W2t, 512, 512);
    transpose_k<<<1024, 256, 0, stream>>>(W3, W3t, 512, 512);

    const double h = 0.1 / 8.0;
    const float A21 = (float)(h * 1.0 / 5.0);
    const float A31 = (float)(h * 3.0 / 40.0),      A32 = (float)(h * 9.0 / 40.0);
    const float A41 = (float)(h * 44.0 / 45.0),     A42 = (float)(h * -56.0 / 15.0);
    const float A43 = (float)(h * 32.0 / 9.0);
    const float A51 = (float)(h * 19372.0 / 6561.0),A52 = (float)(h * -25360.0 / 2187.0);
    const float A53 = (float)(h * 64448.0 / 6561.0),A54 = (float)(h * -212.0 / 729.0);
    const float A61 = (float)(h * 9017.0 / 3168.0), A62 = (float)(h * -355.0 / 33.0);
    const float A63 = (float)(h * 46732.0 / 5247.0),A64 = (float)(h * 49.0 / 176.0);
    const float A65 = (float)(h * -5103.0 / 18656.0);
    const float B1c = (float)(h * 35.0 / 384.0),    B3c = (float)(h * 500.0 / 1113.0);
    const float B4c = (float)(h * 125.0 / 192.0),   B5c = (float)(h * -2187.0 / 6784.0);
    const float B6c = (float)(h * 11.0 / 84.0);

    float* OUT = (float*)d_out;   // fp32 output, per reference dtype

    for (long row0 = 0; row0 < MDIM; row0 += chunk) {
        const long rows = (MDIM - row0 < chunk) ? (MDIM - row0) : chunk;
        const size_t CB = (size_t)rows * NDIM;

        u16* base = ws + wfix;
        float* S32 = (float*)base;          // 2*CB u16
        u16* K1 = base + 2 * CB;
        u16* K2 = base + 3 * CB;
        u16* K3 = base + 4 * CB;
        u16* K4 = base + 5 * CB;
        u16* K5 = base + 6 * CB;
        u16* K6 = K2;                       // k2 dead after stage-6 staging; reuse

        // S32 = u_t @ Wp + bp + y  (fp32 only)
        dim3 gg(4, (unsigned)(rows / 128));
        gemm_bt<256, 3, true><<<gg, 256, 0, stream>>>(
            (const void*)(u_t + (size_t)row0 * 256), Wpt, bp,
            y + (size_t)row0 * NDIM, nullptr, S32);

        const int nb = (int)(rows / 32);    // 32-row tiles -> 2 blocks/CU
        for (int st = 0; st < 8; ++st) {
            // stage 1: k1 = f(S); for st>0 fuse previous step's state update
            if (st == 0)
                ode_eval<0, false><<<nb, 512, 0, stream>>>(
                    S32, nullptr, nullptr, nullptr, nullptr, nullptr, nullptr,
                    0.f, 0.f, 0.f, 0.f, 0.f,
                    W1t, b1, W2t, b2, W3t, b3, K1);
            else
                ode_eval<5, true><<<nb, 512, 0, stream>>>(
                    S32, S32, K1, K3, K4, K5, K6,
                    B1c, B3c, B4c, B5c, B6c,
                    W1t, b1, W2t, b2, W3t, b3, K1);
            ode_eval<1, false><<<nb, 512, 0, stream>>>(
                S32, nullptr, K1, nullptr, nullptr, nullptr, nullptr,
                A21, 0.f, 0.f, 0.f, 0.f,
                W1t, b1, W2t, b2, W3t, b3, K2);
            ode_eval<2, false><<<nb, 512, 0, stream>>>(
                S32, nullptr, K1, K2, nullptr, nullptr, nullptr,
                A31, A32, 0.f, 0.f, 0.f,
                W1t, b1, W2t, b2, W3t, b3, K3);
            ode_eval<3, false><<<nb, 512, 0, stream>>>(
                S32, nullptr, K1, K2, K3, nullptr, nullptr,
                A41, A42, A43, 0.f, 0.f,
                W1t, b1, W2t, b2, W3t, b3, K4);
            ode_eval<4, false><<<nb, 512, 0, stream>>>(
                S32, nullptr, K1, K2, K3, K4, nullptr,
                A51, A52, A53, A54, 0.f,
                W1t, b1, W2t, b2, W3t, b3, K5);
            ode_eval<5, false><<<nb, 512, 0, stream>>>(
                S32, nullptr, K1, K2, K3, K4, K5,
                A61, A62, A63, A64, A65,
                W1t, b1, W2t, b2, W3t, b3, K6);
        }
        // step-8 final state -> output (fp32)
        const int NC = (int)(CB / 4 / 256);
        combo<<<NC, 256, 0, stream>>>(S32, K1, K3, K4, K5, K6,
            B1c, B3c, B4c, B5c, B6c, 5,
            OUT + (size_t)row0 * NDIM, nullptr);
    }
}

// Round 8
// 4593.642 us; speedup vs baseline: 1.5148x; 1.0898x over previous
//
#include <hip/hip_runtime.h>
#include <hip/hip_bf16.h>
#include <cstddef>

typedef unsigned short u16;
typedef short bf16x8 __attribute__((ext_vector_type(8)));   // 8 bf16 bit-patterns (4 VGPRs)
typedef float f32x4 __attribute__((ext_vector_type(4)));
typedef unsigned short u16x8 __attribute__((ext_vector_type(8)));
typedef unsigned short u16x4 __attribute__((ext_vector_type(4)));

#define MDIM 16384
#define NDIM 512
#define HPAD 520   // 512 + 8 elems: row stride 1040 B, breaks b128 bank alignment

__device__ __forceinline__ float b2f(u16 u) {
    return __uint_as_float(((unsigned int)u) << 16);
}
__device__ __forceinline__ u16 f2b(float f) {  // round-to-nearest-even
    unsigned int x = __float_as_uint(f);
    x += 0x7fffu + ((x >> 16) & 1u);
    return (u16)(x >> 16);
}
__device__ __forceinline__ float fast_tanh(float x) {
    // tanh(x) = 1 - 2/(e^{2x}+1); exp overflow -> +1, underflow -> -1 (correct limits)
    float e = __expf(2.0f * x);
    return 1.0f - 2.0f * __builtin_amdgcn_rcpf(e + 1.0f);
}

// ---------------------------------------------------------------------------
// Legacy tiled GEMM (input projection only).
// C(rows x 512) = A(rows x KDIM) * Bt(512 x KDIM)^T + bias(fp32)
// EPI 3: +addf (fp32), write Cf fp32 only        (projection -> state)
template <int KDIM, int EPI, bool AF32>
__global__ __launch_bounds__(256, 2) void gemm_bt(
    const void* __restrict__ Avoid, const u16* __restrict__ Bt,
    const float* __restrict__ bias, const float* __restrict__ addf,
    u16* __restrict__ Cb, float* __restrict__ Cf) {
    __shared__ u16 As[128 * 72];
    __shared__ u16 Bs[128 * 72];
    const int tid = threadIdx.x;
    const int m0 = blockIdx.y * 128;
    const int n0 = blockIdx.x * 128;
    const int lane = tid & 63;
    const int wave = tid >> 6;
    const int wm = (wave & 1) * 64;
    const int wn = (wave >> 1) * 64;
    const int lr = lane & 15;
    const int lk = (lane >> 4) * 8;

    f32x4 acc[4][4];
    f32x4 zero = {0.0f, 0.0f, 0.0f, 0.0f};
#pragma unroll
    for (int i = 0; i < 4; ++i)
#pragma unroll
        for (int j = 0; j < 4; ++j) acc[i][j] = zero;

    const int r0 = tid >> 3;
    const int c0 = (tid & 7) * 8;

    for (int kt = 0; kt < KDIM / 64; ++kt) {
        const int k0 = kt * 64;
#pragma unroll
        for (int it = 0; it < 4; ++it) {
            int r = it * 32 + r0;
            if constexpr (AF32) {
                const float* Af = (const float*)Avoid;
                const float* src = Af + (size_t)(m0 + r) * KDIM + k0 + c0;
                f32x4 lo = *(const f32x4*)(src);
                f32x4 hi = *(const f32x4*)(src + 4);
                u16x8 t;
#pragma unroll
                for (int q = 0; q < 4; ++q) { t[q] = f2b(lo[q]); t[q + 4] = f2b(hi[q]); }
                *(u16x8*)(&As[r * 72 + c0]) = t;
            } else {
                const u16* Ab = (const u16*)Avoid;
                *(f32x4*)(&As[r * 72 + c0]) =
                    *(const f32x4*)(Ab + (size_t)(m0 + r) * KDIM + k0 + c0);
            }
            *(f32x4*)(&Bs[r * 72 + c0]) =
                *(const f32x4*)(Bt + (size_t)(n0 + r) * KDIM + k0 + c0);
        }
        __syncthreads();
#pragma unroll
        for (int kk = 0; kk < 2; ++kk) {
            bf16x8 af[4], bw[4];
#pragma unroll
            for (int i = 0; i < 4; ++i) {
                af[i] = __builtin_bit_cast(
                    bf16x8, *(const f32x4*)(&As[(wm + i * 16 + lr) * 72 + kk * 32 + lk]));
                bw[i] = __builtin_bit_cast(
                    bf16x8, *(const f32x4*)(&Bs[(wn + i * 16 + lr) * 72 + kk * 32 + lk]));
            }
#pragma unroll
            for (int i = 0; i < 4; ++i)
#pragma unroll
                for (int j = 0; j < 4; ++j)
                    acc[i][j] = __builtin_amdgcn_mfma_f32_16x16x32_bf16(
                        af[i], bw[j], acc[i][j], 0, 0, 0);
        }
        __syncthreads();
    }
#pragma unroll
    for (int j = 0; j < 4; ++j) {
        const int col = n0 + wn + j * 16 + lr;
        const float bv = bias[col];
#pragma unroll
        for (int i = 0; i < 4; ++i) {
            const int rowb = m0 + wm + i * 16 + (lane >> 4) * 4;
#pragma unroll
            for (int r = 0; r < 4; ++r) {
                float v = acc[i][j][r] + bv;
                size_t off = (size_t)(rowb + r) * NDIM + col;
                if constexpr (EPI == 2) Cb[off] = f2b(v);
                if constexpr (EPI == 3) {
                    v += addf[off];
                    Cf[off] = v;
                }
            }
        }
    }
}

// ---------------------------------------------------------------------------
// Fully on-chip dopri5 block solver: 32 rows x 8 steps x 6 evals per block.
// 512 threads (8 waves x 64-col strips). Fragment layout everywhere:
//   (i,j,r) <-> row = i*16 + (lane>>4)*4 + r, col = wn + j*16 + (lane&15)
// - S: 32 fp32 regs/thread for the whole solve (read S32 once, OUT once).
// - K1,K4,K5: LDS, fragment-packed [frag][tid] (u16x4 per thread, b64
//   conflict-free). K2,K3: block-local global scratch, same layout,
//   fully coalesced (512 B/wave per access). k6: consumed from acc.
// - Activation: ONE in-place padded LDS buffer (each wave holds its whole
//   layer output in acc[2][4] before write-back; barrier between read & write).
// LDS total = 33,280 + 3*32,768 = 131,584 B -> 1 block/CU; 512 blocks = 2
// rounds. Weight stream from L2 (1.5 MB/block/eval) is the designed wall.
// Same-block global-scratch RAW through __syncthreads: R3-R6-verified pattern.
__global__ __launch_bounds__(512) void ode_block(
    const float* __restrict__ S32,
    const u16* __restrict__ W1t, const float* __restrict__ bb1,
    const u16* __restrict__ W2t, const float* __restrict__ bb2,
    const u16* __restrict__ W3t, const float* __restrict__ bb3,
    u16* __restrict__ K2g, u16* __restrict__ K3g,
    float* __restrict__ OUT) {
    __shared__ u16 As[32 * HPAD];      // 33,280 B
    __shared__ u16 K1L[16384];         // 32,768 B each, fragment-packed
    __shared__ u16 K4L[16384];
    __shared__ u16 K5L[16384];
    const int tid = threadIdx.x;
    const int lane = tid & 63;
    const int wn = (tid >> 6) * 64;    // wave's 64-col strip
    const int lr = lane & 15;
    const int lq = lane >> 4;          // 0..3
    const int lk = lq * 8;
    const size_t row0 = (size_t)blockIdx.x * 32;
    const int off4 = tid * 4;          // u16 offset inside a 2048-u16 frag slab
    u16* K2b = K2g + (size_t)blockIdx.x * 16384;
    u16* K3b = K3g + (size_t)blockIdx.x * 16384;
    u16* K1p = K1L;                    // generic pointers (LDS via flat)
    u16* K4p = K4L;
    u16* K5p = K5L;

    constexpr double h = 0.1 / 8.0;
    constexpr float A21 = (float)(h * 1.0 / 5.0);
    constexpr float A31 = (float)(h * 3.0 / 40.0), A32 = (float)(h * 9.0 / 40.0);
    constexpr float A41 = (float)(h * 44.0 / 45.0), A42 = (float)(h * -56.0 / 15.0);
    constexpr float A43 = (float)(h * 32.0 / 9.0);
    constexpr float A51 = (float)(h * 19372.0 / 6561.0), A52 = (float)(h * -25360.0 / 2187.0);
    constexpr float A53 = (float)(h * 64448.0 / 6561.0), A54 = (float)(h * -212.0 / 729.0);
    constexpr float A61 = (float)(h * 9017.0 / 3168.0), A62 = (float)(h * -355.0 / 33.0);
    constexpr float A63 = (float)(h * 46732.0 / 5247.0), A64 = (float)(h * 49.0 / 176.0);
    constexpr float A65 = (float)(h * -5103.0 / 18656.0);
    constexpr float B1c = (float)(h * 35.0 / 384.0), B3c = (float)(h * 500.0 / 1113.0);
    constexpr float B4c = (float)(h * 125.0 / 192.0), B5c = (float)(h * -2187.0 / 6784.0);
    constexpr float B6c = (float)(h * 11.0 / 84.0);

    const f32x4 zf = {0.f, 0.f, 0.f, 0.f};

    // ---- persistent state in fragment layout (32 regs)
    float S[8][4];
#pragma unroll
    for (int f = 0; f < 8; ++f) {
        const int col = wn + (f & 3) * 16 + lr;
        const int rw = (f >> 2) * 16 + lq * 4;
#pragma unroll
        for (int r = 0; r < 4; ++r)
            S[f][r] = S32[(row0 + rw + r) * 512 + col];
    }

    f32x4 acc[2][4];

// stage: As(row-major) = f2b(S + sum c_t * K_t), K's fragment-packed (LDS or G)
#define STAGE(NT, P0, P1, P2, P3, P4, C0, C1, C2, C3, C4)                          \
    do {                                                                           \
        _Pragma("unroll") for (int f = 0; f < 8; ++f) {                            \
            float sv[4];                                                           \
            _Pragma("unroll") for (int r = 0; r < 4; ++r) sv[r] = S[f][r];         \
            if ((NT) >= 1) {                                                       \
                u16x4 t = *(const u16x4*)((P0) + f * 2048 + off4);                 \
                _Pragma("unroll") for (int r = 0; r < 4; ++r)                      \
                    sv[r] += (C0) * b2f(t[r]);                                     \
            }                                                                      \
            if ((NT) >= 2) {                                                       \
                u16x4 t = *(const u16x4*)((P1) + f * 2048 + off4);                 \
                _Pragma("unroll") for (int r = 0; r < 4; ++r)                      \
                    sv[r] += (C1) * b2f(t[r]);                                     \
            }                                                                      \
            if ((NT) >= 3) {                                                       \
                u16x4 t = *(const u16x4*)((P2) + f * 2048 + off4);                 \
                _Pragma("unroll") for (int r = 0; r < 4; ++r)                      \
                    sv[r] += (C2) * b2f(t[r]);                                     \
            }                                                                      \
            if ((NT) >= 4) {                                                       \
                u16x4 t = *(const u16x4*)((P3) + f * 2048 + off4);                 \
                _Pragma("unroll") for (int r = 0; r < 4; ++r)                      \
                    sv[r] += (C3) * b2f(t[r]);                                     \
            }                                                                      \
            if ((NT) >= 5) {                                                       \
                u16x4 t = *(const u16x4*)((P4) + f * 2048 + off4);                 \
                _Pragma("unroll") for (int r = 0; r < 4; ++r)                      \
                    sv[r] += (C4) * b2f(t[r]);                                     \
            }                                                                      \
            const int col_ = wn + (f & 3) * 16 + lr;                               \
            const int rw_ = (f >> 2) * 16 + lq * 4;                                \
            As[(rw_ + 0) * HPAD + col_] = f2b(sv[0]);                              \
            As[(rw_ + 1) * HPAD + col_] = f2b(sv[1]);                              \
            As[(rw_ + 2) * HPAD + col_] = f2b(sv[2]);                              \
            As[(rw_ + 3) * HPAD + col_] = f2b(sv[3]);                              \
        }                                                                          \
    } while (0)

#define LAYER(WT)                                                                  \
    do {                                                                           \
        _Pragma("unroll") for (int i_ = 0; i_ < 2; ++i_)                           \
            _Pragma("unroll") for (int j_ = 0; j_ < 4; ++j_) acc[i_][j_] = zf;     \
        _Pragma("unroll 4") for (int kt = 0; kt < 16; ++kt) {                      \
            bf16x8 bw[4], af[2];                                                   \
            _Pragma("unroll") for (int j_ = 0; j_ < 4; ++j_)                       \
                bw[j_] = __builtin_bit_cast(bf16x8,                                \
                    *(const f32x4*)((WT) + (size_t)((wn + j_ * 16 + lr) << 9) +    \
                                    kt * 32 + lk));                                \
            _Pragma("unroll") for (int i_ = 0; i_ < 2; ++i_)                       \
                af[i_] = __builtin_bit_cast(bf16x8,                                \
                    *(const f32x4*)(&As[(i_ * 16 + lr) * HPAD + kt * 32 + lk]));   \
            _Pragma("unroll") for (int i_ = 0; i_ < 2; ++i_)                       \
                _Pragma("unroll") for (int j_ = 0; j_ < 4; ++j_)                   \
                    acc[i_][j_] = __builtin_amdgcn_mfma_f32_16x16x32_bf16(         \
                        af[i_], bw[j_], acc[i_][j_], 0, 0, 0);                     \
        }                                                                          \
    } while (0)

// tanh epilogue, in place into As (must be barrier-separated from LAYER reads)
#define EPI_TANH(BIAS)                                                             \
    do {                                                                           \
        _Pragma("unroll") for (int j_ = 0; j_ < 4; ++j_) {                         \
            const float bv = (BIAS)[wn + j_ * 16 + lr];                            \
            _Pragma("unroll") for (int i_ = 0; i_ < 2; ++i_) {                     \
                const int rb = i_ * 16 + lq * 4;                                   \
                const int col_ = wn + j_ * 16 + lr;                                \
                _Pragma("unroll") for (int r_ = 0; r_ < 4; ++r_)                   \
                    As[(rb + r_) * HPAD + col_] =                                  \
                        f2b(fast_tanh(acc[i_][j_][r_] + bv));                      \
            }                                                                      \
        }                                                                          \
    } while (0)

// k epilogue: fragment-packed store (DST = LDS or global, same layout)
#define EPI_K(DST)                                                                 \
    do {                                                                           \
        _Pragma("unroll") for (int i_ = 0; i_ < 2; ++i_)                           \
            _Pragma("unroll") for (int j_ = 0; j_ < 4; ++j_) {                     \
                const float bv = bb3[wn + j_ * 16 + lr];                           \
                u16x4 kv;                                                          \
                _Pragma("unroll") for (int r_ = 0; r_ < 4; ++r_)                   \
                    kv[r_] = f2b(acc[i_][j_][r_] + bv);                            \
                *(u16x4*)((DST) + (i_ * 4 + j_) * 2048 + off4) = kv;               \
            }                                                                      \
    } while (0)

// 3-layer MLP on staged As; leaves layer-3 pre-bias result in acc
#define MLP3                                                                       \
    __syncthreads(); /* As staged / k-store visible */                             \
    LAYER(W1t);                                                                    \
    __syncthreads();                                                               \
    EPI_TANH(bb1);                                                                 \
    __syncthreads();                                                               \
    LAYER(W2t);                                                                    \
    __syncthreads();                                                               \
    EPI_TANH(bb2);                                                                 \
    __syncthreads();                                                               \
    LAYER(W3t);                                                                    \
    __syncthreads(); /* As reads drained; safe to restage / store k */

#pragma clang loop unroll(disable)
    for (int st = 0; st < 8; ++st) {
        // e0: s1 = S -> k1 (LDS)
        STAGE(0, K1p, K1p, K1p, K1p, K1p, 0.f, 0.f, 0.f, 0.f, 0.f);
        MLP3;
        EPI_K(K1p);
        __syncthreads();

        // e1: s2 = S + A21 k1 -> k2 (global)
        STAGE(1, K1p, K1p, K1p, K1p, K1p, A21, 0.f, 0.f, 0.f, 0.f);
        MLP3;
        EPI_K(K2b);
        __syncthreads();

        // e2: s3 = S + A31 k1 + A32 k2 -> k3 (global)
        STAGE(2, K1p, K2b, K2b, K2b, K2b, A31, A32, 0.f, 0.f, 0.f);
        MLP3;
        EPI_K(K3b);
        __syncthreads();

        // e3: s4 = S + A41 k1 + A42 k2 + A43 k3 -> k4 (LDS)
        STAGE(3, K1p, K2b, K3b, K3b, K3b, A41, A42, A43, 0.f, 0.f);
        MLP3;
        EPI_K(K4p);
        __syncthreads();

        // e4: s5 = S + A51 k1 + A52 k2 + A53 k3 + A54 k4 -> k5 (LDS)
        STAGE(4, K1p, K2b, K3b, K4p, K4p, A51, A52, A53, A54, 0.f);
        MLP3;
        EPI_K(K5p);
        __syncthreads();

        // e5: s6 = S + A61 k1 + A62 k2 + A63 k3 + A64 k4 + A65 k5 -> k6 (acc)
        STAGE(5, K1p, K2b, K3b, K4p, K5p, A61, A62, A63, A64, A65);
        MLP3;

        // fused state update: S += B1 k1 + B3 k3 + B4 k4 + B5 k5 + B6 k6
        // (k6 = acc + b3, re-rounded to bf16 to match prior verified numerics)
        {
            const bool last = (st == 7);
#pragma unroll
            for (int i = 0; i < 2; ++i)
#pragma unroll
                for (int j = 0; j < 4; ++j) {
                    const int f = i * 4 + j;
                    const float bv = bb3[wn + j * 16 + lr];
                    u16x4 t1 = *(const u16x4*)(K1p + f * 2048 + off4);
                    u16x4 t3 = *(const u16x4*)(K3b + f * 2048 + off4);
                    u16x4 t4 = *(const u16x4*)(K4p + f * 2048 + off4);
                    u16x4 t5 = *(const u16x4*)(K5p + f * 2048 + off4);
#pragma unroll
                    for (int r = 0; r < 4; ++r) {
                        const float k6 = b2f(f2b(acc[i][j][r] + bv));
                        S[f][r] += B1c * b2f(t1[r]) + B3c * b2f(t3[r]) +
                                   B4c * b2f(t4[r]) + B5c * b2f(t5[r]) + B6c * k6;
                    }
                    if (last) {
                        const int col = wn + j * 16 + lr;
                        const int rw = i * 16 + lq * 4;
#pragma unroll
                        for (int r = 0; r < 4; ++r)
                            OUT[(row0 + rw + r) * 512 + col] = S[f][r];
                    }
                }
        }
    }
#undef MLP3
#undef EPI_K
#undef EPI_TANH
#undef LAYER
#undef STAGE
}

// out_bf16[c*R + r] = in_f32[r*Ncols + c]   (weight transpose + cast, tiny)
__global__ void transpose_k(const float* __restrict__ in, u16* __restrict__ out,
                            int R, int Ncols) {
    int idx = blockIdx.x * 256 + threadIdx.x;
    int r = idx / Ncols, c = idx % Ncols;
    out[(size_t)c * R + r] = f2b(in[idx]);
}

extern "C" void kernel_launch(void* const* d_in, const int* in_sizes, int n_in,
                              void* d_out, int out_size, void* d_ws, size_t ws_size,
                              hipStream_t stream) {
    // ---- order-robust input mapping via in_sizes ----
    const float *y = nullptr, *u_t = nullptr, *Wp = nullptr, *bp = nullptr;
    const float *W1 = nullptr, *b1 = nullptr, *W2 = nullptr, *b2 = nullptr;
    const float *W3 = nullptr, *b3 = nullptr;
    {
        const float* w262[3] = {nullptr, nullptr, nullptr};
        const float* s512[4] = {nullptr, nullptr, nullptr, nullptr};
        int i512[4] = {0, 0, 0, 0};
        int n262 = 0, n512 = 0;
        for (int i = 0; i < n_in; ++i) {
            const float* p = (const float*)d_in[i];
            int sz = in_sizes[i];
            if (sz == MDIM * NDIM) y = p;
            else if (sz == MDIM * 256) u_t = p;
            else if (sz == 256 * 512) Wp = p;
            else if (sz == 512 * 512) { if (n262 < 3) w262[n262++] = p; }
            else if (sz == 512) { if (n512 < 4) { i512[n512] = i; s512[n512++] = p; } }
        }
        W1 = w262[0]; W2 = w262[1]; W3 = w262[2];
        bool contig = (n512 == 4) && (i512[3] == i512[0] + 3);
        if (contig) { b1 = s512[0]; b2 = s512[1]; b3 = s512[2]; bp = s512[3]; }
        else        { bp = s512[0]; b1 = s512[1]; b2 = s512[2]; b3 = s512[3]; }
        if (!y || !u_t || !Wp || !W1 || n512 < 4) {  // fallback: dict order
            y  = (const float*)d_in[0]; u_t = (const float*)d_in[1];
            Wp = (const float*)d_in[2]; bp  = (const float*)d_in[3];
            W1 = (const float*)d_in[4]; b1  = (const float*)d_in[5];
            W2 = (const float*)d_in[6]; b2  = (const float*)d_in[7];
            W3 = (const float*)d_in[8]; b3  = (const float*)d_in[9];
        }
    }

    u16* ws  = (u16*)d_ws;
    u16* Wpt = ws;                    // 512x256 bf16  (N x K, K contiguous)
    u16* W1t = Wpt + 512 * 256;       // 512x512 bf16
    u16* W2t = W1t + 512 * 512;
    u16* W3t = W2t + 512 * 512;
    const size_t wfix = 512 * 256 + 3 * 512 * 512;   // 917504 u16 = 1.84 MB

    // per-row workspace: S32 fp32 (1024 u16) + K2,K3 fragment-packed (2*512 u16)
    long wsElems = (long)(ws_size / 2);
    long chunk = (wsElems - (long)wfix) / (4L * NDIM);
    chunk = (chunk / 128) * 128;
    if (chunk > MDIM) chunk = MDIM;
    if (chunk < 128) chunk = 128;

    transpose_k<<<512, 256, 0, stream>>>(Wp, Wpt, 256, 512);
    transpose_k<<<1024, 256, 0, stream>>>(W1, W1t, 512, 512);
    transpose_k<<<1024, 256, 0, stream>>>(W2, W2t, 512, 512);
    transpose_k<<<1024, 256, 0, stream>>>(W3, W3t, 512, 512);

    float* OUT = (float*)d_out;   // fp32 output, per reference dtype

    for (long row0 = 0; row0 < MDIM; row0 += chunk) {
        const long rows = (MDIM - row0 < chunk) ? (MDIM - row0) : chunk;
        const size_t CB = (size_t)rows * NDIM;

        u16* base = ws + wfix;
        float* S32 = (float*)base;          // 2*CB u16
        u16* K2g = base + 2 * CB;           // CB u16 (rows/32 blocks x 16384)
        u16* K3g = base + 3 * CB;

        // S32 = u_t @ Wp + bp + y  (fp32 only)
        dim3 gg(4, (unsigned)(rows / 128));
        gemm_bt<256, 3, true><<<gg, 256, 0, stream>>>(
            (const void*)(u_t + (size_t)row0 * 256), Wpt, bp,
            y + (size_t)row0 * NDIM, nullptr, S32);

        // whole 8-step solve on-chip per 32-row block
        const int nb = (int)(rows / 32);
        ode_block<<<nb, 512, 0, stream>>>(
            S32, W1t, b1, W2t, b2, W3t, b3,
            K2g, K3g, OUT + (size_t)row0 * NDIM);
    }
}

// Round 9
// 4593.243 us; speedup vs baseline: 1.5149x; 1.0001x over previous
//
#include <hip/hip_runtime.h>
#include <hip/hip_bf16.h>
#include <cstddef>

typedef unsigned short u16;
typedef short bf16x8 __attribute__((ext_vector_type(8)));   // 8 bf16 bit-patterns (4 VGPRs)
typedef float f32x4 __attribute__((ext_vector_type(4)));
typedef unsigned short u16x8 __attribute__((ext_vector_type(8)));
typedef unsigned short u16x4 __attribute__((ext_vector_type(4)));

#define MDIM 16384
#define NDIM 512
#define HPAD 520   // 512 + 8 elems: row stride 1040 B, breaks b128 bank alignment

__device__ __forceinline__ float b2f(u16 u) {
    return __uint_as_float(((unsigned int)u) << 16);
}
__device__ __forceinline__ u16 f2b(float f) {  // round-to-nearest-even
    unsigned int x = __float_as_uint(f);
    x += 0x7fffu + ((x >> 16) & 1u);
    return (u16)(x >> 16);
}
__device__ __forceinline__ float fast_tanh(float x) {
    // tanh(x) = 1 - 2/(e^{2x}+1); exp overflow -> +1, underflow -> -1 (correct limits)
    float e = __expf(2.0f * x);
    return 1.0f - 2.0f * __builtin_amdgcn_rcpf(e + 1.0f);
}

// ---------------------------------------------------------------------------
// Legacy tiled GEMM (input projection only).
// C(rows x 512) = A(rows x KDIM) * Bt(512 x KDIM)^T + bias(fp32)
// EPI 3: +addf (fp32), write Cf fp32 only        (projection -> state)
template <int KDIM, int EPI, bool AF32>
__global__ __launch_bounds__(256, 2) void gemm_bt(
    const void* __restrict__ Avoid, const u16* __restrict__ Bt,
    const float* __restrict__ bias, const float* __restrict__ addf,
    u16* __restrict__ Cb, float* __restrict__ Cf) {
    __shared__ u16 As[128 * 72];
    __shared__ u16 Bs[128 * 72];
    const int tid = threadIdx.x;
    const int m0 = blockIdx.y * 128;
    const int n0 = blockIdx.x * 128;
    const int lane = tid & 63;
    const int wave = tid >> 6;
    const int wm = (wave & 1) * 64;
    const int wn = (wave >> 1) * 64;
    const int lr = lane & 15;
    const int lk = (lane >> 4) * 8;

    f32x4 acc[4][4];
    f32x4 zero = {0.0f, 0.0f, 0.0f, 0.0f};
#pragma unroll
    for (int i = 0; i < 4; ++i)
#pragma unroll
        for (int j = 0; j < 4; ++j) acc[i][j] = zero;

    const int r0 = tid >> 3;
    const int c0 = (tid & 7) * 8;

    for (int kt = 0; kt < KDIM / 64; ++kt) {
        const int k0 = kt * 64;
#pragma unroll
        for (int it = 0; it < 4; ++it) {
            int r = it * 32 + r0;
            if constexpr (AF32) {
                const float* Af = (const float*)Avoid;
                const float* src = Af + (size_t)(m0 + r) * KDIM + k0 + c0;
                f32x4 lo = *(const f32x4*)(src);
                f32x4 hi = *(const f32x4*)(src + 4);
                u16x8 t;
#pragma unroll
                for (int q = 0; q < 4; ++q) { t[q] = f2b(lo[q]); t[q + 4] = f2b(hi[q]); }
                *(u16x8*)(&As[r * 72 + c0]) = t;
            } else {
                const u16* Ab = (const u16*)Avoid;
                *(f32x4*)(&As[r * 72 + c0]) =
                    *(const f32x4*)(Ab + (size_t)(m0 + r) * KDIM + k0 + c0);
            }
            *(f32x4*)(&Bs[r * 72 + c0]) =
                *(const f32x4*)(Bt + (size_t)(n0 + r) * KDIM + k0 + c0);
        }
        __syncthreads();
#pragma unroll
        for (int kk = 0; kk < 2; ++kk) {
            bf16x8 af[4], bw[4];
#pragma unroll
            for (int i = 0; i < 4; ++i) {
                af[i] = __builtin_bit_cast(
                    bf16x8, *(const f32x4*)(&As[(wm + i * 16 + lr) * 72 + kk * 32 + lk]));
                bw[i] = __builtin_bit_cast(
                    bf16x8, *(const f32x4*)(&Bs[(wn + i * 16 + lr) * 72 + kk * 32 + lk]));
            }
#pragma unroll
            for (int i = 0; i < 4; ++i)
#pragma unroll
                for (int j = 0; j < 4; ++j)
                    acc[i][j] = __builtin_amdgcn_mfma_f32_16x16x32_bf16(
                        af[i], bw[j], acc[i][j], 0, 0, 0);
        }
        __syncthreads();
    }
#pragma unroll
    for (int j = 0; j < 4; ++j) {
        const int col = n0 + wn + j * 16 + lr;
        const float bv = bias[col];
#pragma unroll
        for (int i = 0; i < 4; ++i) {
            const int rowb = m0 + wm + i * 16 + (lane >> 4) * 4;
#pragma unroll
            for (int r = 0; r < 4; ++r) {
                float v = acc[i][j][r] + bv;
                size_t off = (size_t)(rowb + r) * NDIM + col;
                if constexpr (EPI == 2) Cb[off] = f2b(v);
                if constexpr (EPI == 3) {
                    v += addf[off];
                    Cf[off] = v;
                }
            }
        }
    }
}

// ---------------------------------------------------------------------------
// On-chip dopri5 block solver, 2-blocks/CU edition.
// 32 rows x 8 steps x 6 evals per block; 512 threads (8 waves x 64-col strips).
// Fragment layout everywhere:
//   (i,j,r) <-> row = i*16 + (lane>>4)*4 + r, col = wn + j*16 + (lane&15)
// - S: 32 fp32 regs/thread for the whole solve (read S32 once, OUT once).
// - K1 (most-read: 6x/step): LDS, fragment-packed [frag][tid] (u16x4/thread).
//   K2..K5: block-local global scratch, same fragment-packed layout, fully
//   coalesced (512 B/wave per access), same-thread RAW only. k6: from acc.
// - Activation: ONE in-place padded LDS buffer (barrier-separated phases).
// LDS = 33,280 (As) + 32,768 (K1) = 66,048 B -> TWO blocks co-resident/CU
// (4 waves/SIMD). In the long-running kernel the two blocks drift out of
// phase across 48 barrier-separated evals, so one block's MFMA/weight-stream
// covers the other's stage/tanh/barrier stalls (m114 overlap) — the config
// R7 (short dispatches, lockstep) and R8 (1 block/CU) could not reach.
// VGPR ~116 <= 128 cap at 4 waves/EU -> no spills (R8-verified live set).
__global__ __launch_bounds__(512, 4) void ode_block(
    const float* __restrict__ S32,
    const u16* __restrict__ W1t, const float* __restrict__ bb1,
    const u16* __restrict__ W2t, const float* __restrict__ bb2,
    const u16* __restrict__ W3t, const float* __restrict__ bb3,
    u16* __restrict__ K2g, u16* __restrict__ K3g,
    u16* __restrict__ K4g, u16* __restrict__ K5g,
    float* __restrict__ OUT) {
    __shared__ u16 As[32 * HPAD];      // 33,280 B
    __shared__ u16 K1L[16384];         // 32,768 B, fragment-packed
    const int tid = threadIdx.x;
    const int lane = tid & 63;
    const int wn = (tid >> 6) * 64;    // wave's 64-col strip
    const int lr = lane & 15;
    const int lq = lane >> 4;          // 0..3
    const int lk = lq * 8;
    const size_t row0 = (size_t)blockIdx.x * 32;
    const int off4 = tid * 4;          // u16 offset inside a 2048-u16 frag slab
    u16* K2b = K2g + (size_t)blockIdx.x * 16384;
    u16* K3b = K3g + (size_t)blockIdx.x * 16384;
    u16* K4b = K4g + (size_t)blockIdx.x * 16384;
    u16* K5b = K5g + (size_t)blockIdx.x * 16384;
    u16* K1p = K1L;                    // generic pointer (LDS via flat)

    constexpr double h = 0.1 / 8.0;
    constexpr float A21 = (float)(h * 1.0 / 5.0);
    constexpr float A31 = (float)(h * 3.0 / 40.0), A32 = (float)(h * 9.0 / 40.0);
    constexpr float A41 = (float)(h * 44.0 / 45.0), A42 = (float)(h * -56.0 / 15.0);
    constexpr float A43 = (float)(h * 32.0 / 9.0);
    constexpr float A51 = (float)(h * 19372.0 / 6561.0), A52 = (float)(h * -25360.0 / 2187.0);
    constexpr float A53 = (float)(h * 64448.0 / 6561.0), A54 = (float)(h * -212.0 / 729.0);
    constexpr float A61 = (float)(h * 9017.0 / 3168.0), A62 = (float)(h * -355.0 / 33.0);
    constexpr float A63 = (float)(h * 46732.0 / 5247.0), A64 = (float)(h * 49.0 / 176.0);
    constexpr float A65 = (float)(h * -5103.0 / 18656.0);
    constexpr float B1c = (float)(h * 35.0 / 384.0), B3c = (float)(h * 500.0 / 1113.0);
    constexpr float B4c = (float)(h * 125.0 / 192.0), B5c = (float)(h * -2187.0 / 6784.0);
    constexpr float B6c = (float)(h * 11.0 / 84.0);

    const f32x4 zf = {0.f, 0.f, 0.f, 0.f};

    // ---- persistent state in fragment layout (32 regs)
    float S[8][4];
#pragma unroll
    for (int f = 0; f < 8; ++f) {
        const int col = wn + (f & 3) * 16 + lr;
        const int rw = (f >> 2) * 16 + lq * 4;
#pragma unroll
        for (int r = 0; r < 4; ++r)
            S[f][r] = S32[(row0 + rw + r) * 512 + col];
    }

    f32x4 acc[2][4];

// stage: As(row-major) = f2b(S + sum c_t * K_t), K's fragment-packed (LDS or G)
#define STAGE(NT, P0, P1, P2, P3, P4, C0, C1, C2, C3, C4)                          \
    do {                                                                           \
        _Pragma("unroll") for (int f = 0; f < 8; ++f) {                            \
            float sv[4];                                                           \
            _Pragma("unroll") for (int r = 0; r < 4; ++r) sv[r] = S[f][r];         \
            if ((NT) >= 1) {                                                       \
                u16x4 t = *(const u16x4*)((P0) + f * 2048 + off4);                 \
                _Pragma("unroll") for (int r = 0; r < 4; ++r)                      \
                    sv[r] += (C0) * b2f(t[r]);                                     \
            }                                                                      \
            if ((NT) >= 2) {                                                       \
                u16x4 t = *(const u16x4*)((P1) + f * 2048 + off4);                 \
                _Pragma("unroll") for (int r = 0; r < 4; ++r)                      \
                    sv[r] += (C1) * b2f(t[r]);                                     \
            }                                                                      \
            if ((NT) >= 3) {                                                       \
                u16x4 t = *(const u16x4*)((P2) + f * 2048 + off4);                 \
                _Pragma("unroll") for (int r = 0; r < 4; ++r)                      \
                    sv[r] += (C2) * b2f(t[r]);                                     \
            }                                                                      \
            if ((NT) >= 4) {                                                       \
                u16x4 t = *(const u16x4*)((P3) + f * 2048 + off4);                 \
                _Pragma("unroll") for (int r = 0; r < 4; ++r)                      \
                    sv[r] += (C3) * b2f(t[r]);                                     \
            }                                                                      \
            if ((NT) >= 5) {                                                       \
                u16x4 t = *(const u16x4*)((P4) + f * 2048 + off4);                 \
                _Pragma("unroll") for (int r = 0; r < 4; ++r)                      \
                    sv[r] += (C4) * b2f(t[r]);                                     \
            }                                                                      \
            const int col_ = wn + (f & 3) * 16 + lr;                               \
            const int rw_ = (f >> 2) * 16 + lq * 4;                                \
            As[(rw_ + 0) * HPAD + col_] = f2b(sv[0]);                              \
            As[(rw_ + 1) * HPAD + col_] = f2b(sv[1]);                              \
            As[(rw_ + 2) * HPAD + col_] = f2b(sv[2]);                              \
            As[(rw_ + 3) * HPAD + col_] = f2b(sv[3]);                              \
        }                                                                          \
    } while (0)

#define LAYER(WT)                                                                  \
    do {                                                                           \
        _Pragma("unroll") for (int i_ = 0; i_ < 2; ++i_)                           \
            _Pragma("unroll") for (int j_ = 0; j_ < 4; ++j_) acc[i_][j_] = zf;     \
        _Pragma("unroll 4") for (int kt = 0; kt < 16; ++kt) {                      \
            bf16x8 bw[4], af[2];                                                   \
            _Pragma("unroll") for (int j_ = 0; j_ < 4; ++j_)                       \
                bw[j_] = __builtin_bit_cast(bf16x8,                                \
                    *(const f32x4*)((WT) + (size_t)((wn + j_ * 16 + lr) << 9) +    \
                                    kt * 32 + lk));                                \
            _Pragma("unroll") for (int i_ = 0; i_ < 2; ++i_)                       \
                af[i_] = __builtin_bit_cast(bf16x8,                                \
                    *(const f32x4*)(&As[(i_ * 16 + lr) * HPAD + kt * 32 + lk]));   \
            _Pragma("unroll") for (int i_ = 0; i_ < 2; ++i_)                       \
                _Pragma("unroll") for (int j_ = 0; j_ < 4; ++j_)                   \
                    acc[i_][j_] = __builtin_amdgcn_mfma_f32_16x16x32_bf16(         \
                        af[i_], bw[j_], acc[i_][j_], 0, 0, 0);                     \
        }                                                                          \
    } while (0)

// tanh epilogue, in place into As (must be barrier-separated from LAYER reads)
#define EPI_TANH(BIAS)                                                             \
    do {                                                                           \
        _Pragma("unroll") for (int j_ = 0; j_ < 4; ++j_) {                         \
            const float bv = (BIAS)[wn + j_ * 16 + lr];                            \
            _Pragma("unroll") for (int i_ = 0; i_ < 2; ++i_) {                     \
                const int rb = i_ * 16 + lq * 4;                                   \
                const int col_ = wn + j_ * 16 + lr;                                \
                _Pragma("unroll") for (int r_ = 0; r_ < 4; ++r_)                   \
                    As[(rb + r_) * HPAD + col_] =                                  \
                        f2b(fast_tanh(acc[i_][j_][r_] + bv));                      \
            }                                                                      \
        }                                                                          \
    } while (0)

// k epilogue: fragment-packed store (DST = LDS or global, same layout)
#define EPI_K(DST)                                                                 \
    do {                                                                           \
        _Pragma("unroll") for (int i_ = 0; i_ < 2; ++i_)                           \
            _Pragma("unroll") for (int j_ = 0; j_ < 4; ++j_) {                     \
                const float bv = bb3[wn + j_ * 16 + lr];                           \
                u16x4 kv;                                                          \
                _Pragma("unroll") for (int r_ = 0; r_ < 4; ++r_)                   \
                    kv[r_] = f2b(acc[i_][j_][r_] + bv);                            \
                *(u16x4*)((DST) + (i_ * 4 + j_) * 2048 + off4) = kv;               \
            }                                                                      \
    } while (0)

// 3-layer MLP on staged As; leaves layer-3 pre-bias result in acc
#define MLP3                                                                       \
    __syncthreads(); /* As staged / k-store visible */                             \
    LAYER(W1t);                                                                    \
    __syncthreads();                                                               \
    EPI_TANH(bb1);                                                                 \
    __syncthreads();                                                               \
    LAYER(W2t);                                                                    \
    __syncthreads();                                                               \
    EPI_TANH(bb2);                                                                 \
    __syncthreads();                                                               \
    LAYER(W3t);                                                                    \
    __syncthreads(); /* As reads drained; safe to restage / store k */

#pragma clang loop unroll(disable)
    for (int st = 0; st < 8; ++st) {
        // e0: s1 = S -> k1 (LDS)
        STAGE(0, K1p, K1p, K1p, K1p, K1p, 0.f, 0.f, 0.f, 0.f, 0.f);
        MLP3;
        EPI_K(K1p);
        __syncthreads();

        // e1: s2 = S + A21 k1 -> k2 (global)
        STAGE(1, K1p, K1p, K1p, K1p, K1p, A21, 0.f, 0.f, 0.f, 0.f);
        MLP3;
        EPI_K(K2b);
        __syncthreads();

        // e2: s3 = S + A31 k1 + A32 k2 -> k3 (global)
        STAGE(2, K1p, K2b, K2b, K2b, K2b, A31, A32, 0.f, 0.f, 0.f);
        MLP3;
        EPI_K(K3b);
        __syncthreads();

        // e3: s4 = S + A41 k1 + A42 k2 + A43 k3 -> k4 (global)
        STAGE(3, K1p, K2b, K3b, K3b, K3b, A41, A42, A43, 0.f, 0.f);
        MLP3;
        EPI_K(K4b);
        __syncthreads();

        // e4: s5 = S + A51 k1 + A52 k2 + A53 k3 + A54 k4 -> k5 (global)
        STAGE(4, K1p, K2b, K3b, K4b, K4b, A51, A52, A53, A54, 0.f);
        MLP3;
        EPI_K(K5b);
        __syncthreads();

        // e5: s6 = S + A61 k1 + A62 k2 + A63 k3 + A64 k4 + A65 k5 -> k6 (acc)
        STAGE(5, K1p, K2b, K3b, K4b, K5b, A61, A62, A63, A64, A65);
        MLP3;

        // fused state update: S += B1 k1 + B3 k3 + B4 k4 + B5 k5 + B6 k6
        // (k6 = acc + b3, re-rounded to bf16 to match prior verified numerics)
        {
            const bool last = (st == 7);
#pragma unroll
            for (int i = 0; i < 2; ++i)
#pragma unroll
                for (int j = 0; j < 4; ++j) {
                    const int f = i * 4 + j;
                    const float bv = bb3[wn + j * 16 + lr];
                    u16x4 t1 = *(const u16x4*)(K1p + f * 2048 + off4);
                    u16x4 t3 = *(const u16x4*)(K3b + f * 2048 + off4);
                    u16x4 t4 = *(const u16x4*)(K4b + f * 2048 + off4);
                    u16x4 t5 = *(const u16x4*)(K5b + f * 2048 + off4);
#pragma unroll
                    for (int r = 0; r < 4; ++r) {
                        const float k6 = b2f(f2b(acc[i][j][r] + bv));
                        S[f][r] += B1c * b2f(t1[r]) + B3c * b2f(t3[r]) +
                                   B4c * b2f(t4[r]) + B5c * b2f(t5[r]) + B6c * k6;
                    }
                    if (last) {
                        const int col = wn + j * 16 + lr;
                        const int rw = i * 16 + lq * 4;
#pragma unroll
                        for (int r = 0; r < 4; ++r)
                            OUT[(row0 + rw + r) * 512 + col] = S[f][r];
                    }
                }
        }
    }
#undef MLP3
#undef EPI_K
#undef EPI_TANH
#undef LAYER
#undef STAGE
}

// out_bf16[c*R + r] = in_f32[r*Ncols + c]   (weight transpose + cast, tiny)
__global__ void transpose_k(const float* __restrict__ in, u16* __restrict__ out,
                            int R, int Ncols) {
    int idx = blockIdx.x * 256 + threadIdx.x;
    int r = idx / Ncols, c = idx % Ncols;
    out[(size_t)c * R + r] = f2b(in[idx]);
}

extern "C" void kernel_launch(void* const* d_in, const int* in_sizes, int n_in,
                              void* d_out, int out_size, void* d_ws, size_t ws_size,
                              hipStream_t stream) {
    // ---- order-robust input mapping via in_sizes ----
    const float *y = nullptr, *u_t = nullptr, *Wp = nullptr, *bp = nullptr;
    const float *W1 = nullptr, *b1 = nullptr, *W2 = nullptr, *b2 = nullptr;
    const float *W3 = nullptr, *b3 = nullptr;
    {
        const float* w262[3] = {nullptr, nullptr, nullptr};
        const float* s512[4] = {nullptr, nullptr, nullptr, nullptr};
        int i512[4] = {0, 0, 0, 0};
        int n262 = 0, n512 = 0;
        for (int i = 0; i < n_in; ++i) {
            const float* p = (const float*)d_in[i];
            int sz = in_sizes[i];
            if (sz == MDIM * NDIM) y = p;
            else if (sz == MDIM * 256) u_t = p;
            else if (sz == 256 * 512) Wp = p;
            else if (sz == 512 * 512) { if (n262 < 3) w262[n262++] = p; }
            else if (sz == 512) { if (n512 < 4) { i512[n512] = i; s512[n512++] = p; } }
        }
        W1 = w262[0]; W2 = w262[1]; W3 = w262[2];
        bool contig = (n512 == 4) && (i512[3] == i512[0] + 3);
        if (contig) { b1 = s512[0]; b2 = s512[1]; b3 = s512[2]; bp = s512[3]; }
        else        { bp = s512[0]; b1 = s512[1]; b2 = s512[2]; b3 = s512[3]; }
        if (!y || !u_t || !Wp || !W1 || n512 < 4) {  // fallback: dict order
            y  = (const float*)d_in[0]; u_t = (const float*)d_in[1];
            Wp = (const float*)d_in[2]; bp  = (const float*)d_in[3];
            W1 = (const float*)d_in[4]; b1  = (const float*)d_in[5];
            W2 = (const float*)d_in[6]; b2  = (const float*)d_in[7];
            W3 = (const float*)d_in[8]; b3  = (const float*)d_in[9];
        }
    }

    u16* ws  = (u16*)d_ws;
    u16* Wpt = ws;                    // 512x256 bf16  (N x K, K contiguous)
    u16* W1t = Wpt + 512 * 256;       // 512x512 bf16
    u16* W2t = W1t + 512 * 512;
    u16* W3t = W2t + 512 * 512;
    const size_t wfix = 512 * 256 + 3 * 512 * 512;   // 917504 u16 = 1.84 MB

    // per-row workspace: S32 fp32 (1024 u16) + K2..K5 fragment-packed (4*512 u16)
    long wsElems = (long)(ws_size / 2);
    long chunk = (wsElems - (long)wfix) / (6L * NDIM);
    chunk = (chunk / 128) * 128;
    if (chunk > MDIM) chunk = MDIM;
    if (chunk < 128) chunk = 128;

    transpose_k<<<512, 256, 0, stream>>>(Wp, Wpt, 256, 512);
    transpose_k<<<1024, 256, 0, stream>>>(W1, W1t, 512, 512);
    transpose_k<<<1024, 256, 0, stream>>>(W2, W2t, 512, 512);
    transpose_k<<<1024, 256, 0, stream>>>(W3, W3t, 512, 512);

    float* OUT = (float*)d_out;   // fp32 output, per reference dtype

    for (long row0 = 0; row0 < MDIM; row0 += chunk) {
        const long rows = (MDIM - row0 < chunk) ? (MDIM - row0) : chunk;
        const size_t CB = (size_t)rows * NDIM;

        u16* base = ws + wfix;
        float* S32 = (float*)base;          // 2*CB u16
        u16* K2g = base + 2 * CB;           // CB u16 each (rows/32 blocks x 16384)
        u16* K3g = base + 3 * CB;
        u16* K4g = base + 4 * CB;
        u16* K5g = base + 5 * CB;

        // S32 = u_t @ Wp + bp + y  (fp32 only)
        dim3 gg(4, (unsigned)(rows / 128));
        gemm_bt<256, 3, true><<<gg, 256, 0, stream>>>(
            (const void*)(u_t + (size_t)row0 * 256), Wpt, bp,
            y + (size_t)row0 * NDIM, nullptr, S32);

        // whole 8-step solve on-chip per 32-row block; 2 blocks/CU resident
        const int nb = (int)(rows / 32);
        ode_block<<<nb, 512, 0, stream>>>(
            S32, W1t, b1, W2t, b2, W3t, b3,
            K2g, K3g, K4g, K5g, OUT + (size_t)row0 * NDIM);
    }
}

// Round 10
// 3041.177 us; speedup vs baseline: 2.2880x; 1.5104x over previous
//
#include <hip/hip_runtime.h>
#include <hip/hip_bf16.h>
#include <cstddef>

typedef unsigned short u16;
typedef short bf16x8 __attribute__((ext_vector_type(8)));   // 8 bf16 bit-patterns (4 VGPRs)
typedef float f32x4 __attribute__((ext_vector_type(4)));
typedef unsigned short u16x8 __attribute__((ext_vector_type(8)));
typedef unsigned short u16x4 __attribute__((ext_vector_type(4)));

#define MDIM 16384
#define NDIM 512
#define HPAD 520   // 512 + 8 elems: row stride 1040 B, breaks b128 bank alignment

__device__ __forceinline__ float b2f(u16 u) {
    return __uint_as_float(((unsigned int)u) << 16);
}
__device__ __forceinline__ u16 f2b(float f) {  // round-to-nearest-even
    unsigned int x = __float_as_uint(f);
    x += 0x7fffu + ((x >> 16) & 1u);
    return (u16)(x >> 16);
}
__device__ __forceinline__ float fast_tanh(float x) {
    // tanh(x) = 1 - 2/(e^{2x}+1); exp overflow -> +1, underflow -> -1 (correct limits)
    float e = __expf(2.0f * x);
    return 1.0f - 2.0f * __builtin_amdgcn_rcpf(e + 1.0f);
}

// ---------------------------------------------------------------------------
// Legacy tiled GEMM (input projection only).
// C(rows x 512) = A(rows x KDIM) * Bt(512 x KDIM)^T + bias(fp32)
// EPI 3: +addf (fp32), write Cf fp32 only        (projection -> state)
template <int KDIM, int EPI, bool AF32>
__global__ __launch_bounds__(256, 2) void gemm_bt(
    const void* __restrict__ Avoid, const u16* __restrict__ Bt,
    const float* __restrict__ bias, const float* __restrict__ addf,
    u16* __restrict__ Cb, float* __restrict__ Cf) {
    __shared__ u16 As[128 * 72];
    __shared__ u16 Bs[128 * 72];
    const int tid = threadIdx.x;
    const int m0 = blockIdx.y * 128;
    const int n0 = blockIdx.x * 128;
    const int lane = tid & 63;
    const int wave = tid >> 6;
    const int wm = (wave & 1) * 64;
    const int wn = (wave >> 1) * 64;
    const int lr = lane & 15;
    const int lk = (lane >> 4) * 8;

    f32x4 acc[4][4];
    f32x4 zero = {0.0f, 0.0f, 0.0f, 0.0f};
#pragma unroll
    for (int i = 0; i < 4; ++i)
#pragma unroll
        for (int j = 0; j < 4; ++j) acc[i][j] = zero;

    const int r0 = tid >> 3;
    const int c0 = (tid & 7) * 8;

    for (int kt = 0; kt < KDIM / 64; ++kt) {
        const int k0 = kt * 64;
#pragma unroll
        for (int it = 0; it < 4; ++it) {
            int r = it * 32 + r0;
            if constexpr (AF32) {
                const float* Af = (const float*)Avoid;
                const float* src = Af + (size_t)(m0 + r) * KDIM + k0 + c0;
                f32x4 lo = *(const f32x4*)(src);
                f32x4 hi = *(const f32x4*)(src + 4);
                u16x8 t;
#pragma unroll
                for (int q = 0; q < 4; ++q) { t[q] = f2b(lo[q]); t[q + 4] = f2b(hi[q]); }
                *(u16x8*)(&As[r * 72 + c0]) = t;
            } else {
                const u16* Ab = (const u16*)Avoid;
                *(f32x4*)(&As[r * 72 + c0]) =
                    *(const f32x4*)(Ab + (size_t)(m0 + r) * KDIM + k0 + c0);
            }
            *(f32x4*)(&Bs[r * 72 + c0]) =
                *(const f32x4*)(Bt + (size_t)(n0 + r) * KDIM + k0 + c0);
        }
        __syncthreads();
#pragma unroll
        for (int kk = 0; kk < 2; ++kk) {
            bf16x8 af[4], bw[4];
#pragma unroll
            for (int i = 0; i < 4; ++i) {
                af[i] = __builtin_bit_cast(
                    bf16x8, *(const f32x4*)(&As[(wm + i * 16 + lr) * 72 + kk * 32 + lk]));
                bw[i] = __builtin_bit_cast(
                    bf16x8, *(const f32x4*)(&Bs[(wn + i * 16 + lr) * 72 + kk * 32 + lk]));
            }
#pragma unroll
            for (int i = 0; i < 4; ++i)
#pragma unroll
                for (int j = 0; j < 4; ++j)
                    acc[i][j] = __builtin_amdgcn_mfma_f32_16x16x32_bf16(
                        af[i], bw[j], acc[i][j], 0, 0, 0);
        }
        __syncthreads();
    }
#pragma unroll
    for (int j = 0; j < 4; ++j) {
        const int col = n0 + wn + j * 16 + lr;
        const float bv = bias[col];
#pragma unroll
        for (int i = 0; i < 4; ++i) {
            const int rowb = m0 + wm + i * 16 + (lane >> 4) * 4;
#pragma unroll
            for (int r = 0; r < 4; ++r) {
                float v = acc[i][j][r] + bv;
                size_t off = (size_t)(rowb + r) * NDIM + col;
                if constexpr (EPI == 2) Cb[off] = f2b(v);
                if constexpr (EPI == 3) {
                    v += addf[off];
                    Cf[off] = v;
                }
            }
        }
    }
}

// ---------------------------------------------------------------------------
// On-chip dopri5 block solver, 64-row / 16-wave edition.
// 64 rows x 8 steps x 6 evals per block; 1024 threads (16 waves, each owns a
// 32-col strip of N=512). Fragment layout:
//   (i,j,r) <-> row = i*16 + (lane>>4)*4 + r, col = wn + j*16 + (lane&15)
//   with i=0..3 (64 rows), j=0..1 (32 cols), wn = wave*32. frag f = i*2+j.
// Rationale (R8/R9 post-mortem): the per-CU weight stream (1.5 MB/eval, 64B
// lines through L1-miss path) is the saturated resource — R9's 2 blocks/CU
// changed nothing. So amortize the FIXED weight stream over 2x rows/block,
// and double miss-level parallelism with 16 waves.
// - S: 32 fp32 regs/thread for the whole solve (read S32 once, OUT once).
// - K1..K5: block-local global scratch, fragment-packed [f][tid] u16x4
//   (off = f*4096 + tid*4 within a 32768-u16 slab) -> every access 512 B/wave
//   contiguous; same-thread RAW only (R4-R9-verified pattern).
// - Activations: As/Hs ping-pong (2 x 64x520 bf16 = 133 KB LDS) -> only 4
//   barriers per eval. 1 block/CU, 4 waves/SIMD.
// - Per-thread live set == R9's measured 64-VGPR budget (S 32 + acc 32 +
//   af/bw 24 overlap) -> no spills at the 128-cap.
__global__ __launch_bounds__(1024, 4) void ode_block(
    const float* __restrict__ S32,
    const u16* __restrict__ W1t, const float* __restrict__ bb1,
    const u16* __restrict__ W2t, const float* __restrict__ bb2,
    const u16* __restrict__ W3t, const float* __restrict__ bb3,
    u16* __restrict__ K1g, u16* __restrict__ K2g, u16* __restrict__ K3g,
    u16* __restrict__ K4g, u16* __restrict__ K5g,
    float* __restrict__ OUT) {
    __shared__ u16 As[64 * HPAD];      // 66,560 B
    __shared__ u16 Hs[64 * HPAD];      // 66,560 B  (total 133,120 B)
    const int tid = threadIdx.x;
    const int lane = tid & 63;
    const int wn = (tid >> 6) * 32;    // wave's 32-col strip
    const int lr = lane & 15;
    const int lq = lane >> 4;          // 0..3
    const int lk = lq * 8;
    const size_t row0 = (size_t)blockIdx.x * 64;
    const int off4 = tid * 4;          // u16 offset inside a 4096-u16 frag slab
    u16* K1b = K1g + (size_t)blockIdx.x * 32768;
    u16* K2b = K2g + (size_t)blockIdx.x * 32768;
    u16* K3b = K3g + (size_t)blockIdx.x * 32768;
    u16* K4b = K4g + (size_t)blockIdx.x * 32768;
    u16* K5b = K5g + (size_t)blockIdx.x * 32768;

    constexpr double h = 0.1 / 8.0;
    constexpr float A21 = (float)(h * 1.0 / 5.0);
    constexpr float A31 = (float)(h * 3.0 / 40.0), A32 = (float)(h * 9.0 / 40.0);
    constexpr float A41 = (float)(h * 44.0 / 45.0), A42 = (float)(h * -56.0 / 15.0);
    constexpr float A43 = (float)(h * 32.0 / 9.0);
    constexpr float A51 = (float)(h * 19372.0 / 6561.0), A52 = (float)(h * -25360.0 / 2187.0);
    constexpr float A53 = (float)(h * 64448.0 / 6561.0), A54 = (float)(h * -212.0 / 729.0);
    constexpr float A61 = (float)(h * 9017.0 / 3168.0), A62 = (float)(h * -355.0 / 33.0);
    constexpr float A63 = (float)(h * 46732.0 / 5247.0), A64 = (float)(h * 49.0 / 176.0);
    constexpr float A65 = (float)(h * -5103.0 / 18656.0);
    constexpr float B1c = (float)(h * 35.0 / 384.0), B3c = (float)(h * 500.0 / 1113.0);
    constexpr float B4c = (float)(h * 125.0 / 192.0), B5c = (float)(h * -2187.0 / 6784.0);
    constexpr float B6c = (float)(h * 11.0 / 84.0);

    const f32x4 zf = {0.f, 0.f, 0.f, 0.f};

    // ---- persistent state in fragment layout (32 regs), f = i*2 + j
    float S[8][4];
#pragma unroll
    for (int f = 0; f < 8; ++f) {
        const int col = wn + (f & 1) * 16 + lr;
        const int rw = (f >> 1) * 16 + lq * 4;
#pragma unroll
        for (int r = 0; r < 4; ++r)
            S[f][r] = S32[(row0 + rw + r) * 512 + col];
    }

    f32x4 acc[4][2];

// stage: DSTL(row-major LDS) = f2b(S + sum c_t * K_t), K's fragment-packed global
#define STAGE(NT, P0, P1, P2, P3, P4, C0, C1, C2, C3, C4)                          \
    do {                                                                           \
        _Pragma("unroll") for (int f = 0; f < 8; ++f) {                            \
            float sv[4];                                                           \
            _Pragma("unroll") for (int r = 0; r < 4; ++r) sv[r] = S[f][r];         \
            if ((NT) >= 1) {                                                       \
                u16x4 t = *(const u16x4*)((P0) + f * 4096 + off4);                 \
                _Pragma("unroll") for (int r = 0; r < 4; ++r)                      \
                    sv[r] += (C0) * b2f(t[r]);                                     \
            }                                                                      \
            if ((NT) >= 2) {                                                       \
                u16x4 t = *(const u16x4*)((P1) + f * 4096 + off4);                 \
                _Pragma("unroll") for (int r = 0; r < 4; ++r)                      \
                    sv[r] += (C1) * b2f(t[r]);                                     \
            }                                                                      \
            if ((NT) >= 3) {                                                       \
                u16x4 t = *(const u16x4*)((P2) + f * 4096 + off4);                 \
                _Pragma("unroll") for (int r = 0; r < 4; ++r)                      \
                    sv[r] += (C2) * b2f(t[r]);                                     \
            }                                                                      \
            if ((NT) >= 4) {                                                       \
                u16x4 t = *(const u16x4*)((P3) + f * 4096 + off4);                 \
                _Pragma("unroll") for (int r = 0; r < 4; ++r)                      \
                    sv[r] += (C3) * b2f(t[r]);                                     \
            }                                                                      \
            if ((NT) >= 5) {                                                       \
                u16x4 t = *(const u16x4*)((P4) + f * 4096 + off4);                 \
                _Pragma("unroll") for (int r = 0; r < 4; ++r)                      \
                    sv[r] += (C4) * b2f(t[r]);                                     \
            }                                                                      \
            const int col_ = wn + (f & 1) * 16 + lr;                               \
            const int rw_ = (f >> 1) * 16 + lq * 4;                                \
            As[(rw_ + 0) * HPAD + col_] = f2b(sv[0]);                              \
            As[(rw_ + 1) * HPAD + col_] = f2b(sv[1]);                              \
            As[(rw_ + 2) * HPAD + col_] = f2b(sv[2]);                              \
            As[(rw_ + 3) * HPAD + col_] = f2b(sv[3]);                              \
        }                                                                          \
    } while (0)

// one MLP layer: SRC(LDS) @ WT^T -> acc;  per wave 4 row-tiles x 2 col-tiles
#define LAYER(SRC, WT)                                                             \
    do {                                                                           \
        _Pragma("unroll") for (int i_ = 0; i_ < 4; ++i_)                           \
            _Pragma("unroll") for (int j_ = 0; j_ < 2; ++j_) acc[i_][j_] = zf;     \
        _Pragma("unroll 4") for (int kt = 0; kt < 16; ++kt) {                      \
            bf16x8 bw[2], af[4];                                                   \
            _Pragma("unroll") for (int j_ = 0; j_ < 2; ++j_)                       \
                bw[j_] = __builtin_bit_cast(bf16x8,                                \
                    *(const f32x4*)((WT) + (size_t)((wn + j_ * 16 + lr) << 9) +    \
                                    kt * 32 + lk));                                \
            _Pragma("unroll") for (int i_ = 0; i_ < 4; ++i_)                       \
                af[i_] = __builtin_bit_cast(bf16x8,                                \
                    *(const f32x4*)(&(SRC)[(i_ * 16 + lr) * HPAD + kt * 32 + lk]));\
            _Pragma("unroll") for (int i_ = 0; i_ < 4; ++i_)                       \
                _Pragma("unroll") for (int j_ = 0; j_ < 2; ++j_)                   \
                    acc[i_][j_] = __builtin_amdgcn_mfma_f32_16x16x32_bf16(         \
                        af[i_], bw[j_], acc[i_][j_], 0, 0, 0);                     \
        }                                                                          \
    } while (0)

// tanh epilogue into DST (the other LDS buffer; no extra barrier needed)
#define EPI_TANH(BIAS, DST)                                                        \
    do {                                                                           \
        _Pragma("unroll") for (int j_ = 0; j_ < 2; ++j_) {                         \
            const float bv = (BIAS)[wn + j_ * 16 + lr];                            \
            _Pragma("unroll") for (int i_ = 0; i_ < 4; ++i_) {                     \
                const int rb = i_ * 16 + lq * 4;                                   \
                const int col_ = wn + j_ * 16 + lr;                                \
                _Pragma("unroll") for (int r_ = 0; r_ < 4; ++r_)                   \
                    (DST)[(rb + r_) * HPAD + col_] =                               \
                        f2b(fast_tanh(acc[i_][j_][r_] + bv));                      \
            }                                                                      \
        }                                                                          \
    } while (0)

// k epilogue: fragment-packed coalesced global store (same-thread slots)
#define EPI_K(DST)                                                                 \
    do {                                                                           \
        _Pragma("unroll") for (int i_ = 0; i_ < 4; ++i_)                           \
            _Pragma("unroll") for (int j_ = 0; j_ < 2; ++j_) {                     \
                const float bv = bb3[wn + j_ * 16 + lr];                           \
                u16x4 kv;                                                          \
                _Pragma("unroll") for (int r_ = 0; r_ < 4; ++r_)                   \
                    kv[r_] = f2b(acc[i_][j_][r_] + bv);                            \
                *(u16x4*)((DST) + (i_ * 2 + j_) * 4096 + off4) = kv;               \
            }                                                                      \
    } while (0)

// 3-layer MLP on staged As; leaves layer-3 pre-bias result in acc.
// Barriers: B1 (stage->L1), B2 (L1->L2), B3 (L2->L3), B4 (L3 reads drained).
#define MLP3                                                                       \
    __syncthreads();                                                               \
    LAYER(As, W1t);                                                                \
    EPI_TANH(bb1, Hs);                                                             \
    __syncthreads();                                                               \
    LAYER(Hs, W2t);                                                                \
    EPI_TANH(bb2, As);                                                             \
    __syncthreads();                                                               \
    LAYER(As, W3t);                                                                \
    __syncthreads();

#pragma clang loop unroll(disable)
    for (int st = 0; st < 8; ++st) {
        // e0: s1 = S -> k1
        STAGE(0, K1b, K1b, K1b, K1b, K1b, 0.f, 0.f, 0.f, 0.f, 0.f);
        MLP3;
        EPI_K(K1b);

        // e1: s2 = S + A21 k1 -> k2
        STAGE(1, K1b, K1b, K1b, K1b, K1b, A21, 0.f, 0.f, 0.f, 0.f);
        MLP3;
        EPI_K(K2b);

        // e2: s3 = S + A31 k1 + A32 k2 -> k3
        STAGE(2, K1b, K2b, K2b, K2b, K2b, A31, A32, 0.f, 0.f, 0.f);
        MLP3;
        EPI_K(K3b);

        // e3: s4 = S + A41 k1 + A42 k2 + A43 k3 -> k4
        STAGE(3, K1b, K2b, K3b, K3b, K3b, A41, A42, A43, 0.f, 0.f);
        MLP3;
        EPI_K(K4b);

        // e4: s5 = S + A51 k1 + A52 k2 + A53 k3 + A54 k4 -> k5
        STAGE(4, K1b, K2b, K3b, K4b, K4b, A51, A52, A53, A54, 0.f);
        MLP3;
        EPI_K(K5b);

        // e5: s6 = S + A61 k1 + A62 k2 + A63 k3 + A64 k4 + A65 k5 -> k6 (acc)
        STAGE(5, K1b, K2b, K3b, K4b, K5b, A61, A62, A63, A64, A65);
        MLP3;

        // fused state update: S += B1 k1 + B3 k3 + B4 k4 + B5 k5 + B6 k6
        // (k6 = acc + b3, re-rounded to bf16 -> matches prior verified numerics)
        {
            const bool last = (st == 7);
#pragma unroll
            for (int i = 0; i < 4; ++i)
#pragma unroll
                for (int j = 0; j < 2; ++j) {
                    const int f = i * 2 + j;
                    const float bv = bb3[wn + j * 16 + lr];
                    u16x4 t1 = *(const u16x4*)(K1b + f * 4096 + off4);
                    u16x4 t3 = *(const u16x4*)(K3b + f * 4096 + off4);
                    u16x4 t4 = *(const u16x4*)(K4b + f * 4096 + off4);
                    u16x4 t5 = *(const u16x4*)(K5b + f * 4096 + off4);
#pragma unroll
                    for (int r = 0; r < 4; ++r) {
                        const float k6 = b2f(f2b(acc[i][j][r] + bv));
                        S[f][r] += B1c * b2f(t1[r]) + B3c * b2f(t3[r]) +
                                   B4c * b2f(t4[r]) + B5c * b2f(t5[r]) + B6c * k6;
                    }
                    if (last) {
                        const int col = wn + j * 16 + lr;
                        const int rw = i * 16 + lq * 4;
#pragma unroll
                        for (int r = 0; r < 4; ++r)
                            OUT[(row0 + rw + r) * 512 + col] = S[f][r];
                    }
                }
        }
    }
#undef MLP3
#undef EPI_K
#undef EPI_TANH
#undef LAYER
#undef STAGE
}

// out_bf16[c*R + r] = in_f32[r*Ncols + c]   (weight transpose + cast, tiny)
__global__ void transpose_k(const float* __restrict__ in, u16* __restrict__ out,
                            int R, int Ncols) {
    int idx = blockIdx.x * 256 + threadIdx.x;
    int r = idx / Ncols, c = idx % Ncols;
    out[(size_t)c * R + r] = f2b(in[idx]);
}

extern "C" void kernel_launch(void* const* d_in, const int* in_sizes, int n_in,
                              void* d_out, int out_size, void* d_ws, size_t ws_size,
                              hipStream_t stream) {
    // ---- order-robust input mapping via in_sizes ----
    const float *y = nullptr, *u_t = nullptr, *Wp = nullptr, *bp = nullptr;
    const float *W1 = nullptr, *b1 = nullptr, *W2 = nullptr, *b2 = nullptr;
    const float *W3 = nullptr, *b3 = nullptr;
    {
        const float* w262[3] = {nullptr, nullptr, nullptr};
        const float* s512[4] = {nullptr, nullptr, nullptr, nullptr};
        int i512[4] = {0, 0, 0, 0};
        int n262 = 0, n512 = 0;
        for (int i = 0; i < n_in; ++i) {
            const float* p = (const float*)d_in[i];
            int sz = in_sizes[i];
            if (sz == MDIM * NDIM) y = p;
            else if (sz == MDIM * 256) u_t = p;
            else if (sz == 256 * 512) Wp = p;
            else if (sz == 512 * 512) { if (n262 < 3) w262[n262++] = p; }
            else if (sz == 512) { if (n512 < 4) { i512[n512] = i; s512[n512++] = p; } }
        }
        W1 = w262[0]; W2 = w262[1]; W3 = w262[2];
        bool contig = (n512 == 4) && (i512[3] == i512[0] + 3);
        if (contig) { b1 = s512[0]; b2 = s512[1]; b3 = s512[2]; bp = s512[3]; }
        else        { bp = s512[0]; b1 = s512[1]; b2 = s512[2]; b3 = s512[3]; }
        if (!y || !u_t || !Wp || !W1 || n512 < 4) {  // fallback: dict order
            y  = (const float*)d_in[0]; u_t = (const float*)d_in[1];
            Wp = (const float*)d_in[2]; bp  = (const float*)d_in[3];
            W1 = (const float*)d_in[4]; b1  = (const float*)d_in[5];
            W2 = (const float*)d_in[6]; b2  = (const float*)d_in[7];
            W3 = (const float*)d_in[8]; b3  = (const float*)d_in[9];
        }
    }

    u16* ws  = (u16*)d_ws;
    u16* Wpt = ws;                    // 512x256 bf16  (N x K, K contiguous)
    u16* W1t = Wpt + 512 * 256;       // 512x512 bf16
    u16* W2t = W1t + 512 * 512;
    u16* W3t = W2t + 512 * 512;
    const size_t wfix = 512 * 256 + 3 * 512 * 512;   // 917504 u16 = 1.84 MB

    // per-row workspace: S32 fp32 (1024 u16) + K1..K5 fragment-packed (5*512 u16)
    long wsElems = (long)(ws_size / 2);
    long chunk = (wsElems - (long)wfix) / (7L * NDIM);
    chunk = (chunk / 128) * 128;
    if (chunk > MDIM) chunk = MDIM;
    if (chunk < 128) chunk = 128;

    transpose_k<<<512, 256, 0, stream>>>(Wp, Wpt, 256, 512);
    transpose_k<<<1024, 256, 0, stream>>>(W1, W1t, 512, 512);
    transpose_k<<<1024, 256, 0, stream>>>(W2, W2t, 512, 512);
    transpose_k<<<1024, 256, 0, stream>>>(W3, W3t, 512, 512);

    float* OUT = (float*)d_out;   // fp32 output, per reference dtype

    for (long row0 = 0; row0 < MDIM; row0 += chunk) {
        const long rows = (MDIM - row0 < chunk) ? (MDIM - row0) : chunk;
        const size_t CB = (size_t)rows * NDIM;

        u16* base = ws + wfix;
        float* S32 = (float*)base;          // 2*CB u16
        u16* K1g = base + 2 * CB;           // CB u16 each (rows/64 blocks x 32768)
        u16* K2g = base + 3 * CB;
        u16* K3g = base + 4 * CB;
        u16* K4g = base + 5 * CB;
        u16* K5g = base + 6 * CB;

        // S32 = u_t @ Wp + bp + y  (fp32 only)
        dim3 gg(4, (unsigned)(rows / 128));
        gemm_bt<256, 3, true><<<gg, 256, 0, stream>>>(
            (const void*)(u_t + (size_t)row0 * 256), Wpt, bp,
            y + (size_t)row0 * NDIM, nullptr, S32);

        // whole 8-step solve on-chip per 64-row block; 1 block/CU, 16 waves
        const int nb = (int)(rows / 64);
        ode_block<<<nb, 1024, 0, stream>>>(
            S32, W1t, b1, W2t, b2, W3t, b3,
            K1g, K2g, K3g, K4g, K5g, OUT + (size_t)row0 * NDIM);
    }
}